// Round 5
// baseline (1172.021 us; speedup 1.0000x reference)
//
#include <hip/hip_runtime.h>
#include <stdint.h>

#define NB3 8112
#define NB4 2028
#define NB5 507
#define NTOT 10647           // 8112 + 2028 + 507
#define NBATCH 4
#define NCLS 20
#define NW32 333             // ceil(10647 / 32)
#define NW64 167             // ceil(10647 / 64)
#define TRIW 897792          // 64 * (167*168/2) words per triangle per image
#define LDS_CAP 9984         // boxes staged in LDS (fallback kernel)
#define CONF_THR_F 0.1f
#define IOU_THR_F 0.45f

typedef unsigned long long u64;

// ---------------------------------------------------------------------------
// Kernel A: per-box score / class argmax / sort key
// ---------------------------------------------------------------------------
__global__ void prep_kernel(const float* __restrict__ p3b, const float* __restrict__ p3c, const float* __restrict__ p3k,
                            const float* __restrict__ p4b, const float* __restrict__ p4c, const float* __restrict__ p4k,
                            const float* __restrict__ p5b, const float* __restrict__ p5c, const float* __restrict__ p5k,
                            uint64_t* __restrict__ keys, float4* __restrict__ boxes_cat,
                            float* __restrict__ score, int* __restrict__ clsidx, uint32_t* __restrict__ svout)
{
#pragma clang fp contract(off)
    int idx = blockIdx.x * 256 + threadIdx.x;
    if (idx >= NBATCH * NTOT) return;
    int b = idx / NTOT;
    int i = idx - b * NTOT;

    const float* bx; const float* cf; const float* cl; int n, off;
    if (i < NB3)            { bx = p3b; cf = p3c; cl = p3k; n = NB3; off = i; }
    else if (i < NB3 + NB4) { bx = p4b; cf = p4c; cl = p4k; n = NB4; off = i - NB3; }
    else                    { bx = p5b; cf = p5c; cl = p5k; n = NB5; off = i - NB3 - NB4; }

    size_t e = (size_t)b * n + off;
    float4 box = *(const float4*)(bx + e * 4);
    float conf = cf[e];
    const float* c = cl + e * NCLS;
    float m = c[0]; int mi = 0;
    #pragma unroll
    for (int k = 1; k < NCLS; ++k) { float v = c[k]; if (v > m) { m = v; mi = k; } }

    bool valid = conf > CONF_THR_F;
    float s = valid ? conf * m : 0.0f;           // exact: single f32 mul, no fma
    uint32_t sb = __float_as_uint(s);            // s >= 0 -> bits monotonic
    keys[idx]      = ((uint64_t)sb << 32) | (uint32_t)(0xFFFFFFFFu - (uint32_t)i);
    boxes_cat[idx] = box;
    score[idx]     = s;
    clsidx[idx]    = mi;
    svout[idx]     = valid ? 1u : 0u;
}

// ---------------------------------------------------------------------------
// Kernel B: stable descending rank sort (rank = #keys strictly greater),
// scatter sorted arrays, build valid bitmap (u64 words) per image
// ---------------------------------------------------------------------------
__global__ void rank_kernel(const uint64_t* __restrict__ keys,
                            const float4* __restrict__ boxes_cat,
                            const float* __restrict__ score,
                            const int* __restrict__ clsidx,
                            const uint32_t* __restrict__ sv,
                            float4* __restrict__ sboxes, float* __restrict__ sscore,
                            int* __restrict__ scls, uint32_t* __restrict__ ssv,
                            u64* __restrict__ validbits, int* __restrict__ nvalid)
{
    int b = blockIdx.y;
    int i = blockIdx.x * 256 + threadIdx.x;
    const uint64_t* kb = keys + (size_t)b * NTOT;
    uint64_t mykey = (i < NTOT) ? kb[i] : 0ull;

    __shared__ uint64_t tile[256];
    int rank = 0;
    for (int t0 = 0; t0 < NTOT; t0 += 256) {
        int j = t0 + threadIdx.x;
        tile[threadIdx.x] = (j < NTOT) ? kb[j] : 0ull;   // 0 never > any real key
        __syncthreads();
        #pragma unroll 8
        for (int t = 0; t < 256; ++t) rank += (tile[t] > mykey) ? 1 : 0;
        __syncthreads();
    }

    if (i < NTOT) {
        size_t src = (size_t)b * NTOT + i;
        size_t dst = (size_t)b * NTOT + rank;
        sboxes[dst] = boxes_cat[src];
        sscore[dst] = score[src];
        scls[dst]   = clsidx[src];
        uint32_t v  = sv[src];
        ssv[dst]    = v;
        if (v) {
            atomicOr(&validbits[(size_t)b * NW64 + (rank >> 6)], 1ull << (rank & 63));
            atomicMax(&nvalid[b], rank + 1);
        }
    }
}

// ---------------------------------------------------------------------------
// Kernel C1 (fast path): build BOTH triangles of the suppression matrix,
// stored triangularly (each triangle = TRIW u64 words per image):
//  mup (upper, row-OR side): row i, words w in [i>>6, NW64):
//    idx = 64*(g*NW64 - g*(g-1)/2) + (i&63)*(NW64-g) + (w-g), g = i>>6.
//    bit k of word w: IoU(i, w*64+k) > thr && w*64+k > i && w*64+k < NTOT.
//  mlo (lower, column-test side): row j, words w in [0, j>>6]:
//    idx = 32*g*(g+1) + (j&63)*(g+1) + w, g = j>>6.
//    bit k: IoU(j, w*64+k) > thr && w*64+k < j && valid[w*64+k].
//  hasup[b][g] bit l: row g*64+l has ANY earlier valid suppressor
//    (ballot-aggregated; lets resolve round 0 skip all scanning).
// Both triangles compute IoU with identical operand order -> bit-identical.
// ---------------------------------------------------------------------------
__global__ void __launch_bounds__(256) mask_build(const float4* __restrict__ sboxes,
                                                  const u64* __restrict__ validbits,
                                                  u64* __restrict__ mup,
                                                  u64* __restrict__ mlo,
                                                  u64* __restrict__ hasup)
{
#pragma clang fp contract(off)
    int c = blockIdx.y;
    int b = blockIdx.z;
    int sub = threadIdx.x >> 6;
    int lane = threadIdx.x & 63;
    int r = blockIdx.x * 4 + sub;

    __shared__ float4 cb[64];
    __shared__ float  ca[64];
    if (threadIdx.x < 64) {
        int j = c * 64 + threadIdx.x;
        float4 bj = sboxes[(size_t)b * NTOT + (j < NTOT ? j : NTOT - 1)];
        cb[threadIdx.x] = bj;
        ca[threadIdx.x] = (bj.z - bj.x) * (bj.w - bj.y);
    }
    __syncthreads();

    if (r >= NW64) return;
    int i = r * 64 + lane;
    bool live = (i < NTOT);
    float4 bi = sboxes[(size_t)b * NTOT + (live ? i : NTOT - 1)];
    float ax1 = bi.x, ay1 = bi.y, ax2 = bi.z, ay2 = bi.w;
    float area_i = (ax2 - ax1) * (ay2 - ay1);
    u64 vw = validbits[(size_t)b * NW64 + c];

    u64 mu = 0, ml = 0;
    #pragma unroll 8
    for (int k = 0; k < 64; ++k) {
        float4 bj = cb[k];
        float xx1 = fmaxf(bj.x, ax1);
        float yy1 = fmaxf(bj.y, ay1);
        float xx2 = fminf(bj.z, ax2);
        float yy2 = fminf(bj.w, ay2);
        float w = fmaxf(xx2 - xx1, 0.0f);
        float h = fmaxf(yy2 - yy1, 0.0f);
        float inter = w * h;
        float iou = inter / ((area_i + ca[k]) - inter);   // matches ref op order
        bool hit = iou > IOU_THR_F;
        mu |= (u64)(hit && (c > r || k > lane) && (c * 64 + k < NTOT)) << k;
        ml |= (u64)(hit && (c < r || k < lane) && ((vw >> k) & 1ull)) << k;
    }

    if (c >= r && live) {
        size_t upbase = (size_t)64 * ((size_t)r * NW64 - ((size_t)r * (r - 1)) / 2);
        mup[(size_t)b * TRIW + upbase + (size_t)lane * (NW64 - r) + (c - r)] = mu;
    }
    if (c <= r) {
        if (live) {
            size_t lobase = (size_t)32 * r * (r + 1);
            mlo[(size_t)b * TRIW + lobase + (size_t)lane * (r + 1) + c] = ml;
        }
        u64 bal = __ballot(live && ml != 0);
        if (lane == 0 && bal)
            atomicOr((unsigned long long*)&hasup[(size_t)b * NW64 + r], (unsigned long long)bal);
    }
}

// ---------------------------------------------------------------------------
// Kernel C2 (fast path): fixpoint greedy resolve, one 1024-thread block per
// image. Replaces the ~2000-step serial greedy chain (the measured floor of
// rounds 1-4) with D parallel rounds (D = suppression-DAG decision depth):
//   invariant: R = OR of rows of decided-kept boxes (monotone increasing).
//   j decided-kept  <=> all earlier valid suppressors of j are in R
//                       (column test on mlo row j, resume-pointer'd).
//   j decided-removed <=> R bit j set (some decided-kept row covers j).
//   Round 0 uses hasup: boxes with no earlier valid suppressor are kept
//   without any scan. Progress: the minimal pending box is decided every
//   round -> terminates in <= NTOT rounds (practically D).
// Phase A scans in 8-word chunks so load latency is paid once per chunk,
// not once per word; wcur makes rechecks O(1 chunk).
// ---------------------------------------------------------------------------
__global__ void __launch_bounds__(1024) resolve_kernel(const u64* __restrict__ mup,
                                                       const u64* __restrict__ mlo,
                                                       const u64* __restrict__ hasup,
                                                       const u64* __restrict__ validbits,
                                                       u64* __restrict__ rem_out)
{
    int b = blockIdx.x;
    int tid = threadIdx.x;
    const u64* MU = mup + (size_t)b * TRIW;
    const u64* ML = mlo + (size_t)b * TRIW;
    const u64* V  = validbits + (size_t)b * NW64;
    const u64* H  = hasup + (size_t)b * NW64;

    __shared__ u64 R[NW64];
    __shared__ u64 hs[NW64];
    __shared__ int klist[10688];
    __shared__ int nNew;
    __shared__ int morePend;

    for (int t = tid; t < NW64; t += 1024) { R[t] = 0ull; hs[t] = H[t]; }

    unsigned char  st[11];                     // 0 = pending, 1 = decided
    unsigned short wc[11];                     // resume word pointer
    #pragma unroll
    for (int s = 0; s < 11; ++s) {
        int j = tid + (s << 10);
        bool pend = false;
        if (j < NTOT) pend = (V[j >> 6] >> (j & 63)) & 1ull;
        st[s] = pend ? 0 : 1;
        wc[s] = 0;
    }
    if (tid == 0) { nNew = 0; morePend = 0; }
    __syncthreads();

    for (int round = 0; round < NTOT; ++round) {
        // ---------------- Phase A: column tests ----------------
        #pragma unroll
        for (int s = 0; s < 11; ++s) {
            if (st[s]) continue;
            int j = tid + (s << 10);
            int g = j >> 6, jb = j & 63;
            if ((R[g] >> jb) & 1ull) { st[s] = 1; continue; }   // removed

            bool blocked;
            if (round == 0) {
                blocked = (hs[g] >> jb) & 1ull;                 // free round-0 test
            } else {
                const u64* row = ML + (size_t)32 * g * (g + 1) + (size_t)jb * (g + 1);
                int w = wc[s];
                blocked = false;
                while (w <= g) {
                    u64 tt[8];
                    #pragma unroll
                    for (int q = 0; q < 8; ++q) {
                        int ww = w + q;
                        tt[q] = (ww <= g) ? (row[ww] & ~R[ww]) : 0ull;
                    }
                    u64 any = 0;
                    #pragma unroll
                    for (int q = 0; q < 8; ++q) any |= tt[q];
                    if (any) {
                        int qf = 7;
                        #pragma unroll
                        for (int q = 7; q >= 0; --q) if (tt[q]) qf = q;
                        w += qf;
                        blocked = true;
                        break;
                    }
                    w += 8;
                }
                wc[s] = (unsigned short)w;
            }
            if (!blocked) {
                st[s] = 1;
                int pos = atomicAdd(&nNew, 1);
                klist[pos] = j;                                  // decided-kept
            } else {
                morePend = 1;
            }
        }
        __syncthreads();                        // klist/nNew/morePend stable
        int nn = nNew;
        int mp = morePend;

        // ---------------- Phase B: row-OR of newly-kept ----------------
        for (int p = tid; p < nn * NW64; p += 1024) {
            int s2 = p / NW64;
            int w  = p - s2 * NW64;
            int rr = klist[s2];
            int g  = rr >> 6;
            if (w >= g) {
                size_t upbase = (size_t)64 * ((size_t)g * NW64 - ((size_t)g * (g - 1)) / 2);
                u64 m = MU[upbase + (size_t)(rr & 63) * (NW64 - g) + (w - g)];
                if (m) atomicOr((unsigned long long*)&R[w], (unsigned long long)m);
            }
        }
        __syncthreads();                        // R stable; all have read mp/nn
        if (!mp) break;
        if (tid == 0) { nNew = 0; morePend = 0; }
        __syncthreads();                        // reset visible before next A
    }

    for (int t = tid; t < NW64; t += 1024)
        rem_out[(size_t)b * NW64 + t] = R[t];
}

// ---------------------------------------------------------------------------
// Fallback (small ws): original single-block NMS. Writes u32 words into the
// same u64 rem buffer (little-endian layout makes bit positions identical).
// ---------------------------------------------------------------------------
extern __shared__ unsigned char nms_smem[];

__global__ void __launch_bounds__(1024) nms_kernel(const float4* __restrict__ sboxes,
                                                   const uint32_t* __restrict__ ssv,
                                                   const int* __restrict__ nvalid_arr,
                                                   uint32_t* __restrict__ supp_out)
{
#pragma clang fp contract(off)
    int b = blockIdx.x;
    float4*   lbox = (float4*)nms_smem;
    uint32_t* supp = (uint32_t*)(nms_smem + (size_t)LDS_CAP * 16);
    uint32_t* svb  = supp + NW32;

    int nv = nvalid_arr[b];
    const float4* gb = sboxes + (size_t)b * NTOT;
    const uint32_t* gv = ssv + (size_t)b * NTOT;

    for (int t = threadIdx.x; t < NW32; t += 1024) { supp[t] = 0u; svb[t] = 0u; }
    __syncthreads();
    for (int t = threadIdx.x; t < nv; t += 1024) {
        if (t < LDS_CAP) lbox[t] = gb[t];
        if (gv[t]) atomicOr(&svb[t >> 5], 1u << (t & 31));
    }
    __syncthreads();

    for (int i = 0; i < nv; ++i) {
        uint32_t sw = supp[i >> 5];
        if ((sw >> (i & 31)) & 1u) continue;
        uint32_t vw = svb[i >> 5];
        if (!((vw >> (i & 31)) & 1u)) continue;

        float4 bi = (i < LDS_CAP) ? lbox[i] : gb[i];
        float ax1 = bi.x, ay1 = bi.y, ax2 = bi.z, ay2 = bi.w;
        float area_i = (ax2 - ax1) * (ay2 - ay1);

        for (int j = i + 1 + (int)threadIdx.x; j < nv; j += 1024) {
            float4 bj = (j < LDS_CAP) ? lbox[j] : gb[j];
            float xx1 = fmaxf(bj.x, ax1);
            float yy1 = fmaxf(bj.y, ay1);
            float xx2 = fminf(bj.z, ax2);
            float yy2 = fminf(bj.w, ay2);
            float w = fmaxf(xx2 - xx1, 0.0f);
            float h = fmaxf(yy2 - yy1, 0.0f);
            float inter  = w * h;
            float area_j = (bj.z - bj.x) * (bj.w - bj.y);
            float iou = inter / ((area_i + area_j) - inter);
            if (iou > IOU_THR_F) atomicOr(&supp[j >> 5], 1u << (j & 31));
        }
        __syncthreads();
    }

    __syncthreads();
    // u64 layout: u32 word w of image b lives at u32-index b*(2*NW64) + w
    for (int t = threadIdx.x; t < NW32; t += 1024)
        supp_out[(size_t)b * (2 * NW64) + t] = supp[t];
}

// ---------------------------------------------------------------------------
// Kernel D: assemble outputs: dets [B,N,6] then keep [B,N] (as 0/1 floats)
// ---------------------------------------------------------------------------
__global__ void out_kernel(const float4* __restrict__ sboxes, const float* __restrict__ sscore,
                           const int* __restrict__ scls, const uint32_t* __restrict__ ssv,
                           const u64* __restrict__ rem, float* __restrict__ out)
{
    int idx = blockIdx.x * 256 + threadIdx.x;
    if (idx >= NBATCH * NTOT) return;
    int b = idx / NTOT;
    int p = idx - b * NTOT;

    float4 box = sboxes[idx];
    u64 rw = rem[(size_t)b * NW64 + (p >> 6)];
    bool keep = (ssv[idx] != 0u) && !((rw >> (p & 63)) & 1ull);
    float sc = keep ? sscore[idx] : 0.0f;

    float* d = out + (size_t)idx * 6;
    d[0] = box.x; d[1] = box.y; d[2] = box.z; d[3] = box.w;
    d[4] = sc;    d[5] = (float)scls[idx];
    out[(size_t)NBATCH * NTOT * 6 + idx] = keep ? 1.0f : 0.0f;
}

// ---------------------------------------------------------------------------
extern "C" void kernel_launch(void* const* d_in, const int* in_sizes, int n_in,
                              void* d_out, int out_size, void* d_ws, size_t ws_size,
                              hipStream_t stream)
{
    const float* p3b = (const float*)d_in[0];
    const float* p3c = (const float*)d_in[1];
    const float* p3k = (const float*)d_in[2];
    const float* p4b = (const float*)d_in[3];
    const float* p4c = (const float*)d_in[4];
    const float* p4k = (const float*)d_in[5];
    const float* p5b = (const float*)d_in[6];
    const float* p5c = (const float*)d_in[7];
    const float* p5k = (const float*)d_in[8];
    float* out = (float*)d_out;

    // workspace carve-up (256B aligned slabs)
    char* ws = (char*)d_ws;
    size_t off = 0;
    auto alloc = [&](size_t bytes) { size_t o = off; off += (bytes + 255) & ~(size_t)255; return o; };
    const size_t BN = (size_t)NBATCH * NTOT;
    uint64_t* keys      = (uint64_t*)(ws + alloc(BN * 8));
    float4*   boxes_cat = (float4*)  (ws + alloc(BN * 16));
    float*    score     = (float*)   (ws + alloc(BN * 4));
    int*      clsidx    = (int*)     (ws + alloc(BN * 4));
    uint32_t* sv        = (uint32_t*)(ws + alloc(BN * 4));
    float4*   sboxes    = (float4*)  (ws + alloc(BN * 16));
    float*    sscore    = (float*)   (ws + alloc(BN * 4));
    int*      scls      = (int*)     (ws + alloc(BN * 4));
    uint32_t* ssv       = (uint32_t*)(ws + alloc(BN * 4));
    u64*      rem64     = (u64*)     (ws + alloc((size_t)NBATCH * NW64 * 8));
    u64*      validbits = (u64*)     (ws + alloc((size_t)NBATCH * NW64 * 8));
    u64*      hasup     = (u64*)     (ws + alloc((size_t)NBATCH * NW64 * 8));
    int*      nvalid    = (int*)     (ws + alloc(NBATCH * 4));
    u64*      mup       = (u64*)     (ws + alloc((size_t)NBATCH * TRIW * 8));
    u64*      mlo       = (u64*)     (ws + alloc((size_t)NBATCH * TRIW * 8));
    bool fast = (off <= ws_size);

    hipMemsetAsync(nvalid, 0, NBATCH * 4, stream);
    hipMemsetAsync(validbits, 0, (size_t)NBATCH * NW64 * 8, stream);
    hipMemsetAsync(hasup, 0, (size_t)NBATCH * NW64 * 8, stream);

    int nblk = (int)((BN + 255) / 256);
    prep_kernel<<<nblk, 256, 0, stream>>>(p3b, p3c, p3k, p4b, p4c, p4k, p5b, p5c, p5k,
                                          keys, boxes_cat, score, clsidx, sv);

    dim3 rgrid((NTOT + 255) / 256, NBATCH);
    rank_kernel<<<rgrid, 256, 0, stream>>>(keys, boxes_cat, score, clsidx, sv,
                                           sboxes, sscore, scls, ssv, validbits, nvalid);

    if (fast) {
        dim3 mgrid((NW64 + 3) / 4, NW64, NBATCH);
        mask_build<<<mgrid, 256, 0, stream>>>(sboxes, validbits, mup, mlo, hasup);
        resolve_kernel<<<NBATCH, 1024, 0, stream>>>(mup, mlo, hasup, validbits, rem64);
    } else {
        hipMemsetAsync(rem64, 0, (size_t)NBATCH * NW64 * 8, stream);
        size_t smem = (size_t)LDS_CAP * 16 + (size_t)NW32 * 4 * 2;
        smem = (smem + 15) & ~(size_t)15;
        hipFuncSetAttribute((const void*)nms_kernel, hipFuncAttributeMaxDynamicSharedMemorySize, (int)smem);
        nms_kernel<<<NBATCH, 1024, smem, stream>>>(sboxes, ssv, nvalid, (uint32_t*)rem64);
    }

    out_kernel<<<nblk, 256, 0, stream>>>(sboxes, sscore, scls, ssv, rem64, out);
}

// Round 6
// 1064.709 us; speedup vs baseline: 1.1008x; 1.1008x over previous
//
#include <hip/hip_runtime.h>
#include <stdint.h>

#define NB3 8112
#define NB4 2028
#define NB5 507
#define NTOT 10647           // 8112 + 2028 + 507
#define NBATCH 4
#define NCLS 20
#define NW32 333             // ceil(10647 / 32)
#define NW64 167             // ceil(10647 / 64)
#define NTAIL 23             // NTOT - 64*(NW64-1)
#define TRIW 897792          // 64 * (167*168/2) words per triangle per image
#define LDS_CAP 9984         // boxes staged in LDS (fallback kernel)
#define CONF_THR_F 0.1f
#define IOU_THR_F 0.45f

typedef unsigned long long u64;

// ---------------------------------------------------------------------------
// Kernel A: per-box score / class argmax / sort key
// ---------------------------------------------------------------------------
__global__ void prep_kernel(const float* __restrict__ p3b, const float* __restrict__ p3c, const float* __restrict__ p3k,
                            const float* __restrict__ p4b, const float* __restrict__ p4c, const float* __restrict__ p4k,
                            const float* __restrict__ p5b, const float* __restrict__ p5c, const float* __restrict__ p5k,
                            uint64_t* __restrict__ keys, float4* __restrict__ boxes_cat,
                            float* __restrict__ score, int* __restrict__ clsidx, uint32_t* __restrict__ svout)
{
#pragma clang fp contract(off)
    int idx = blockIdx.x * 256 + threadIdx.x;
    if (idx >= NBATCH * NTOT) return;
    int b = idx / NTOT;
    int i = idx - b * NTOT;

    const float* bx; const float* cf; const float* cl; int n, off;
    if (i < NB3)            { bx = p3b; cf = p3c; cl = p3k; n = NB3; off = i; }
    else if (i < NB3 + NB4) { bx = p4b; cf = p4c; cl = p4k; n = NB4; off = i - NB3; }
    else                    { bx = p5b; cf = p5c; cl = p5k; n = NB5; off = i - NB3 - NB4; }

    size_t e = (size_t)b * n + off;
    float4 box = *(const float4*)(bx + e * 4);
    float conf = cf[e];
    const float* c = cl + e * NCLS;
    float m = c[0]; int mi = 0;
    #pragma unroll
    for (int k = 1; k < NCLS; ++k) { float v = c[k]; if (v > m) { m = v; mi = k; } }

    bool valid = conf > CONF_THR_F;
    float s = valid ? conf * m : 0.0f;           // exact: single f32 mul, no fma
    uint32_t sb = __float_as_uint(s);            // s >= 0 -> bits monotonic
    keys[idx]      = ((uint64_t)sb << 32) | (uint32_t)(0xFFFFFFFFu - (uint32_t)i);
    boxes_cat[idx] = box;
    score[idx]     = s;
    clsidx[idx]    = mi;
    svout[idx]     = valid ? 1u : 0u;
}

// ---------------------------------------------------------------------------
// Kernel B: stable descending rank sort (rank = #keys strictly greater),
// scatter sorted arrays, build valid bitmap (u64 words) per image
// ---------------------------------------------------------------------------
__global__ void rank_kernel(const uint64_t* __restrict__ keys,
                            const float4* __restrict__ boxes_cat,
                            const float* __restrict__ score,
                            const int* __restrict__ clsidx,
                            const uint32_t* __restrict__ sv,
                            float4* __restrict__ sboxes, float* __restrict__ sscore,
                            int* __restrict__ scls, uint32_t* __restrict__ ssv,
                            u64* __restrict__ validbits, int* __restrict__ nvalid)
{
    int b = blockIdx.y;
    int i = blockIdx.x * 256 + threadIdx.x;
    const uint64_t* kb = keys + (size_t)b * NTOT;
    uint64_t mykey = (i < NTOT) ? kb[i] : 0ull;

    __shared__ uint64_t tile[256];
    int rank = 0;
    for (int t0 = 0; t0 < NTOT; t0 += 256) {
        int j = t0 + threadIdx.x;
        tile[threadIdx.x] = (j < NTOT) ? kb[j] : 0ull;   // 0 never > any real key
        __syncthreads();
        #pragma unroll 8
        for (int t = 0; t < 256; ++t) rank += (tile[t] > mykey) ? 1 : 0;
        __syncthreads();
    }

    if (i < NTOT) {
        size_t src = (size_t)b * NTOT + i;
        size_t dst = (size_t)b * NTOT + rank;
        sboxes[dst] = boxes_cat[src];
        sscore[dst] = score[src];
        scls[dst]   = clsidx[src];
        uint32_t v  = sv[src];
        ssv[dst]    = v;
        if (v) {
            atomicOr(&validbits[(size_t)b * NW64 + (rank >> 6)], 1ull << (rank & 63));
            atomicMax(&nvalid[b], rank + 1);
        }
    }
}

// ---------------------------------------------------------------------------
// Kernel C1 (fast path): build both triangles, computing each IoU tile ONCE.
//  mup (upper, row-OR side): row i, words w in [i>>6, NW64):
//    idx = 64*(g*NW64 - g*(g-1)/2) + (i&63)*(NW64-g) + (w-g), g = i>>6.
//  mlo (lower, column-test side): row j, words w in [0, j>>6]:
//    idx = 32*g*(g+1) + (j&63)*(g+1) + w, g = j>>6. Bits masked by valid[].
//  hasup[b][g] bit l: row g*64+l has ANY earlier valid suppressor.
// Upper blocks (c > r) compute the 64x64 hit tile once and derive the
// mirrored mlo tile by 64-ballot bit-transpose (IoU is bit-symmetric:
// fadd/fmax commute). Blocks strictly below the diagonal are skipped.
// ---------------------------------------------------------------------------
__global__ void __launch_bounds__(256) mask_build(const float4* __restrict__ sboxes,
                                                  const u64* __restrict__ validbits,
                                                  u64* __restrict__ mup,
                                                  u64* __restrict__ mlo,
                                                  u64* __restrict__ hasup)
{
#pragma clang fp contract(off)
    int c = blockIdx.y;
    if (c < blockIdx.x * 4) return;              // whole stripe below diagonal
    int b = blockIdx.z;
    int sub = threadIdx.x >> 6;
    int lane = threadIdx.x & 63;
    int r = blockIdx.x * 4 + sub;

    __shared__ float4 cb[64];
    __shared__ float  ca[64];
    if (threadIdx.x < 64) {
        int j = c * 64 + threadIdx.x;
        float4 bj = sboxes[(size_t)b * NTOT + (j < NTOT ? j : NTOT - 1)];
        cb[threadIdx.x] = bj;
        ca[threadIdx.x] = (bj.z - bj.x) * (bj.w - bj.y);
    }
    __syncthreads();

    if (r >= NW64 || c < r) return;              // wave below diagonal / OOB
    int i = r * 64 + lane;
    bool live = (i < NTOT);
    float4 bi = sboxes[(size_t)b * NTOT + (live ? i : NTOT - 1)];
    float ax1 = bi.x, ay1 = bi.y, ax2 = bi.z, ay2 = bi.w;
    float area_i = (ax2 - ax1) * (ay2 - ay1);

    u64 h = 0;
    #pragma unroll 8
    for (int k = 0; k < 64; ++k) {
        float4 bj = cb[k];
        float xx1 = fmaxf(bj.x, ax1);
        float yy1 = fmaxf(bj.y, ay1);
        float xx2 = fminf(bj.z, ax2);
        float yy2 = fminf(bj.w, ay2);
        float w = fmaxf(xx2 - xx1, 0.0f);
        float hh = fmaxf(yy2 - yy1, 0.0f);
        float inter = w * hh;
        float iou = inter / ((area_i + ca[k]) - inter);   // matches ref op order
        h |= (u64)(iou > IOU_THR_F) << k;
    }

    u64 colmask = (c == NW64 - 1) ? ((1ull << NTAIL) - 1) : ~0ull;
    size_t upbase = (size_t)64 * ((size_t)r * NW64 - ((size_t)r * (r - 1)) / 2);

    if (c == r) {
        u64 gtmask = (lane < 63) ? (~0ull << (lane + 1)) : 0ull;
        u64 ltmask = (1ull << lane) - 1;
        u64 vw = validbits[(size_t)b * NW64 + r];
        u64 mu = h & gtmask & colmask;
        u64 ml = h & ltmask & vw;
        if (live) {
            mup[(size_t)b * TRIW + upbase + (size_t)lane * (NW64 - r)] = mu;
            mlo[(size_t)b * TRIW + (size_t)32 * r * (r + 1) + (size_t)lane * (r + 1) + r] = ml;
        }
        u64 bal = __ballot(live && ml != 0ull);
        if (lane == 0 && bal)
            atomicOr((unsigned long long*)&hasup[(size_t)b * NW64 + r], (unsigned long long)bal);
    } else {
        u64 mu = h & colmask;
        if (live)
            mup[(size_t)b * TRIW + upbase + (size_t)lane * (NW64 - r) + (c - r)] = mu;
        // bit-transpose: mlw (for row j = c*64+lane, word r): bit l = h[l][k=lane]
        u64 mlw = 0;
        #pragma unroll 8
        for (int k = 0; k < 64; ++k) {
            u64 bw = __ballot((h >> k) & 1ull);
            if (lane == k) mlw = bw;
        }
        mlw &= validbits[(size_t)b * NW64 + r];   // earlier boxes i=r*64+l must be valid
        int j = c * 64 + lane;
        if (j < NTOT)
            mlo[(size_t)b * TRIW + (size_t)32 * c * (c + 1) + (size_t)lane * (c + 1) + r] = mlw;
        u64 bal = __ballot((j < NTOT) && mlw != 0ull);
        if (lane == 0 && bal)
            atomicOr((unsigned long long*)&hasup[(size_t)b * NW64 + c], (unsigned long long)bal);
    }
}

// ---------------------------------------------------------------------------
// Kernel C2 (fast path): fixpoint greedy resolve, one 1024-thread block per
// image. Same monotone fixpoint as round 5 (provably == greedy NMS), but the
// steady-state round is LDS/VALU-only:
//  * each pending slot caches its current BLOCKING WORD VALUE (cw) + index
//    (wc). Per-round re-test = cw & ~R[wc]: 1 LDS read, no global traffic.
//  * global loads happen only when the scan ADVANCES -> each mlo row word is
//    fetched at most once over the whole kernel.
//  * 2 barriers/round via parity-indexed nNew/morePend counters.
//  * round 0 decides all unconstrained boxes via hasup (no scan).
// ---------------------------------------------------------------------------
__global__ void __launch_bounds__(1024) resolve_kernel(const u64* __restrict__ mup,
                                                       const u64* __restrict__ mlo,
                                                       const u64* __restrict__ hasup,
                                                       const u64* __restrict__ validbits,
                                                       u64* __restrict__ rem_out)
{
    int b = blockIdx.x;
    int tid = threadIdx.x;
    const u64* MU = mup + (size_t)b * TRIW;
    const u64* ML = mlo + (size_t)b * TRIW;
    const u64* V  = validbits + (size_t)b * NW64;
    const u64* H  = hasup + (size_t)b * NW64;

    __shared__ u64 R[NW64 + 3];                  // +3 pad: chunked test may index past g
    __shared__ u64 hs[NW64];
    __shared__ int klist[10688];
    __shared__ int nNew[2];
    __shared__ int morePend[2];

    for (int t = tid; t < NW64; t += 1024) { R[t] = 0ull; hs[t] = H[t]; }
    if (tid < 2) { R[NW64 + tid] = 0ull; nNew[tid] = 0; morePend[tid] = 0; }
    if (tid == 2) R[NW64 + 2] = 0ull;

    unsigned char  st[11];                       // 0 = pending, 1 = decided
    unsigned short wc[11];                       // word index of cached blocker / resume
    u64            cw[11];                       // cached blocking word (0 = none)
    #pragma unroll
    for (int s = 0; s < 11; ++s) {
        int j = tid + (s << 10);
        bool pend = false;
        if (j < NTOT) pend = (V[j >> 6] >> (j & 63)) & 1ull;
        st[s] = pend ? 0 : 1;
        wc[s] = 0;
        cw[s] = 0ull;
    }
    __syncthreads();

    for (int round = 0; round < NTOT; ++round) {
        int par = round & 1;

        // ---------------- Phase A: column tests ----------------
        #pragma unroll
        for (int s = 0; s < 11; ++s) {
            if (st[s]) continue;
            int j = tid + (s << 10);
            int g = j >> 6, jb = j & 63;
            if ((R[g] >> jb) & 1ull) { st[s] = 1; continue; }   // removed

            bool blocked;
            if (round == 0) {
                blocked = (hs[g] >> jb) & 1ull;                 // free round-0 test
            } else {
                blocked = false;
                int w = wc[s];
                if (cw[s]) {
                    if (cw[s] & ~R[w]) blocked = true;          // steady state: LDS only
                    else { cw[s] = 0ull; ++w; }
                }
                if (!blocked) {
                    const u64* row = ML + (size_t)32 * g * (g + 1) + (size_t)jb * (g + 1);
                    while (w <= g) {
                        u64 t0 = row[w];
                        u64 t1 = (w + 1 <= g) ? row[w + 1] : 0ull;
                        u64 t2 = (w + 2 <= g) ? row[w + 2] : 0ull;
                        u64 t3 = (w + 3 <= g) ? row[w + 3] : 0ull;
                        u64 m0 = t0 & ~R[w];
                        u64 m1 = t1 & ~R[w + 1];
                        u64 m2 = t2 & ~R[w + 2];
                        u64 m3 = t3 & ~R[w + 3];
                        if (m0 | m1 | m2 | m3) {
                            if      (m0) { cw[s] = t0; wc[s] = (unsigned short)w; }
                            else if (m1) { cw[s] = t1; wc[s] = (unsigned short)(w + 1); }
                            else if (m2) { cw[s] = t2; wc[s] = (unsigned short)(w + 2); }
                            else         { cw[s] = t3; wc[s] = (unsigned short)(w + 3); }
                            blocked = true;
                            break;
                        }
                        w += 4;
                    }
                }
            }
            if (!blocked) {
                st[s] = 1;
                int pos = atomicAdd(&nNew[par], 1);
                klist[pos] = j;                                  // decided-kept
            } else {
                morePend[par] = 1;
            }
        }
        __syncthreads();                        // klist/counters stable
        int nn = nNew[par];
        int mp = morePend[par];
        if (tid == 0) { nNew[par ^ 1] = 0; morePend[par ^ 1] = 0; }

        // ---------------- Phase B: row-OR of newly-kept ----------------
        for (int p = tid; p < nn * NW64; p += 1024) {
            int s2 = p / NW64;
            int w  = p - s2 * NW64;
            int rr = klist[s2];
            int g  = rr >> 6;
            if (w >= g) {
                size_t upbase = (size_t)64 * ((size_t)g * NW64 - ((size_t)g * (g - 1)) / 2);
                u64 m = MU[upbase + (size_t)(rr & 63) * (NW64 - g) + (w - g)];
                if (m) atomicOr((unsigned long long*)&R[w], (unsigned long long)m);
            }
        }
        __syncthreads();                        // R stable; resets visible next round
        if (!mp) break;
    }

    for (int t = tid; t < NW64; t += 1024)
        rem_out[(size_t)b * NW64 + t] = R[t];
}

// ---------------------------------------------------------------------------
// Fallback (small ws): original single-block NMS. Writes u32 words into the
// same u64 rem buffer (little-endian layout makes bit positions identical).
// ---------------------------------------------------------------------------
extern __shared__ unsigned char nms_smem[];

__global__ void __launch_bounds__(1024) nms_kernel(const float4* __restrict__ sboxes,
                                                   const uint32_t* __restrict__ ssv,
                                                   const int* __restrict__ nvalid_arr,
                                                   uint32_t* __restrict__ supp_out)
{
#pragma clang fp contract(off)
    int b = blockIdx.x;
    float4*   lbox = (float4*)nms_smem;
    uint32_t* supp = (uint32_t*)(nms_smem + (size_t)LDS_CAP * 16);
    uint32_t* svb  = supp + NW32;

    int nv = nvalid_arr[b];
    const float4* gb = sboxes + (size_t)b * NTOT;
    const uint32_t* gv = ssv + (size_t)b * NTOT;

    for (int t = threadIdx.x; t < NW32; t += 1024) { supp[t] = 0u; svb[t] = 0u; }
    __syncthreads();
    for (int t = threadIdx.x; t < nv; t += 1024) {
        if (t < LDS_CAP) lbox[t] = gb[t];
        if (gv[t]) atomicOr(&svb[t >> 5], 1u << (t & 31));
    }
    __syncthreads();

    for (int i = 0; i < nv; ++i) {
        uint32_t sw = supp[i >> 5];
        if ((sw >> (i & 31)) & 1u) continue;
        uint32_t vw = svb[i >> 5];
        if (!((vw >> (i & 31)) & 1u)) continue;

        float4 bi = (i < LDS_CAP) ? lbox[i] : gb[i];
        float ax1 = bi.x, ay1 = bi.y, ax2 = bi.z, ay2 = bi.w;
        float area_i = (ax2 - ax1) * (ay2 - ay1);

        for (int j = i + 1 + (int)threadIdx.x; j < nv; j += 1024) {
            float4 bj = (j < LDS_CAP) ? lbox[j] : gb[j];
            float xx1 = fmaxf(bj.x, ax1);
            float yy1 = fmaxf(bj.y, ay1);
            float xx2 = fminf(bj.z, ax2);
            float yy2 = fminf(bj.w, ay2);
            float w = fmaxf(xx2 - xx1, 0.0f);
            float h = fmaxf(yy2 - yy1, 0.0f);
            float inter  = w * h;
            float area_j = (bj.z - bj.x) * (bj.w - bj.y);
            float iou = inter / ((area_i + area_j) - inter);
            if (iou > IOU_THR_F) atomicOr(&supp[j >> 5], 1u << (j & 31));
        }
        __syncthreads();
    }

    __syncthreads();
    // u64 layout: u32 word w of image b lives at u32-index b*(2*NW64) + w
    for (int t = threadIdx.x; t < NW32; t += 1024)
        supp_out[(size_t)b * (2 * NW64) + t] = supp[t];
}

// ---------------------------------------------------------------------------
// Kernel D: assemble outputs: dets [B,N,6] then keep [B,N] (as 0/1 floats)
// ---------------------------------------------------------------------------
__global__ void out_kernel(const float4* __restrict__ sboxes, const float* __restrict__ sscore,
                           const int* __restrict__ scls, const uint32_t* __restrict__ ssv,
                           const u64* __restrict__ rem, float* __restrict__ out)
{
    int idx = blockIdx.x * 256 + threadIdx.x;
    if (idx >= NBATCH * NTOT) return;
    int b = idx / NTOT;
    int p = idx - b * NTOT;

    float4 box = sboxes[idx];
    u64 rw = rem[(size_t)b * NW64 + (p >> 6)];
    bool keep = (ssv[idx] != 0u) && !((rw >> (p & 63)) & 1ull);
    float sc = keep ? sscore[idx] : 0.0f;

    float* d = out + (size_t)idx * 6;
    d[0] = box.x; d[1] = box.y; d[2] = box.z; d[3] = box.w;
    d[4] = sc;    d[5] = (float)scls[idx];
    out[(size_t)NBATCH * NTOT * 6 + idx] = keep ? 1.0f : 0.0f;
}

// ---------------------------------------------------------------------------
extern "C" void kernel_launch(void* const* d_in, const int* in_sizes, int n_in,
                              void* d_out, int out_size, void* d_ws, size_t ws_size,
                              hipStream_t stream)
{
    const float* p3b = (const float*)d_in[0];
    const float* p3c = (const float*)d_in[1];
    const float* p3k = (const float*)d_in[2];
    const float* p4b = (const float*)d_in[3];
    const float* p4c = (const float*)d_in[4];
    const float* p4k = (const float*)d_in[5];
    const float* p5b = (const float*)d_in[6];
    const float* p5c = (const float*)d_in[7];
    const float* p5k = (const float*)d_in[8];
    float* out = (float*)d_out;

    // workspace carve-up (256B aligned slabs)
    char* ws = (char*)d_ws;
    size_t off = 0;
    auto alloc = [&](size_t bytes) { size_t o = off; off += (bytes + 255) & ~(size_t)255; return o; };
    const size_t BN = (size_t)NBATCH * NTOT;
    uint64_t* keys      = (uint64_t*)(ws + alloc(BN * 8));
    float4*   boxes_cat = (float4*)  (ws + alloc(BN * 16));
    float*    score     = (float*)   (ws + alloc(BN * 4));
    int*      clsidx    = (int*)     (ws + alloc(BN * 4));
    uint32_t* sv        = (uint32_t*)(ws + alloc(BN * 4));
    float4*   sboxes    = (float4*)  (ws + alloc(BN * 16));
    float*    sscore    = (float*)   (ws + alloc(BN * 4));
    int*      scls      = (int*)     (ws + alloc(BN * 4));
    uint32_t* ssv       = (uint32_t*)(ws + alloc(BN * 4));
    u64*      rem64     = (u64*)     (ws + alloc((size_t)NBATCH * NW64 * 8));
    u64*      validbits = (u64*)     (ws + alloc((size_t)NBATCH * NW64 * 8));
    u64*      hasup     = (u64*)     (ws + alloc((size_t)NBATCH * NW64 * 8));
    int*      nvalid    = (int*)     (ws + alloc(NBATCH * 4));
    u64*      mup       = (u64*)     (ws + alloc((size_t)NBATCH * TRIW * 8));
    u64*      mlo       = (u64*)     (ws + alloc((size_t)NBATCH * TRIW * 8));
    bool fast = (off <= ws_size);

    hipMemsetAsync(nvalid, 0, NBATCH * 4, stream);
    hipMemsetAsync(validbits, 0, (size_t)NBATCH * NW64 * 8, stream);
    hipMemsetAsync(hasup, 0, (size_t)NBATCH * NW64 * 8, stream);

    int nblk = (int)((BN + 255) / 256);
    prep_kernel<<<nblk, 256, 0, stream>>>(p3b, p3c, p3k, p4b, p4c, p4k, p5b, p5c, p5k,
                                          keys, boxes_cat, score, clsidx, sv);

    dim3 rgrid((NTOT + 255) / 256, NBATCH);
    rank_kernel<<<rgrid, 256, 0, stream>>>(keys, boxes_cat, score, clsidx, sv,
                                           sboxes, sscore, scls, ssv, validbits, nvalid);

    if (fast) {
        dim3 mgrid((NW64 + 3) / 4, NW64, NBATCH);
        mask_build<<<mgrid, 256, 0, stream>>>(sboxes, validbits, mup, mlo, hasup);
        resolve_kernel<<<NBATCH, 1024, 0, stream>>>(mup, mlo, hasup, validbits, rem64);
    } else {
        hipMemsetAsync(rem64, 0, (size_t)NBATCH * NW64 * 8, stream);
        size_t smem = (size_t)LDS_CAP * 16 + (size_t)NW32 * 4 * 2;
        smem = (smem + 15) & ~(size_t)15;
        hipFuncSetAttribute((const void*)nms_kernel, hipFuncAttributeMaxDynamicSharedMemorySize, (int)smem);
        nms_kernel<<<NBATCH, 1024, smem, stream>>>(sboxes, ssv, nvalid, (uint32_t*)rem64);
    }

    out_kernel<<<nblk, 256, 0, stream>>>(sboxes, sscore, scls, ssv, rem64, out);
}

// Round 7
// 976.438 us; speedup vs baseline: 1.2003x; 1.0904x over previous
//
#include <hip/hip_runtime.h>
#include <stdint.h>

#define NB3 8112
#define NB4 2028
#define NB5 507
#define NTOT 10647           // 8112 + 2028 + 507
#define NBATCH 4
#define NCLS 20
#define NW32 333             // ceil(10647 / 32)
#define NW64 167             // ceil(10647 / 64)
#define LDS_CAP 9984         // boxes staged in LDS (fallback kernel)
#define CONF_THR_F 0.1f
#define IOU_THR_F 0.45f

typedef unsigned long long u64;

// ---------------------------------------------------------------------------
// Kernel A: per-box score / class argmax / sort key
// ---------------------------------------------------------------------------
__global__ void prep_kernel(const float* __restrict__ p3b, const float* __restrict__ p3c, const float* __restrict__ p3k,
                            const float* __restrict__ p4b, const float* __restrict__ p4c, const float* __restrict__ p4k,
                            const float* __restrict__ p5b, const float* __restrict__ p5c, const float* __restrict__ p5k,
                            uint64_t* __restrict__ keys, float4* __restrict__ boxes_cat,
                            float* __restrict__ score, int* __restrict__ clsidx, uint32_t* __restrict__ svout)
{
#pragma clang fp contract(off)
    int idx = blockIdx.x * 256 + threadIdx.x;
    if (idx >= NBATCH * NTOT) return;
    int b = idx / NTOT;
    int i = idx - b * NTOT;

    const float* bx; const float* cf; const float* cl; int n, off;
    if (i < NB3)            { bx = p3b; cf = p3c; cl = p3k; n = NB3; off = i; }
    else if (i < NB3 + NB4) { bx = p4b; cf = p4c; cl = p4k; n = NB4; off = i - NB3; }
    else                    { bx = p5b; cf = p5c; cl = p5k; n = NB5; off = i - NB3 - NB4; }

    size_t e = (size_t)b * n + off;
    float4 box = *(const float4*)(bx + e * 4);
    float conf = cf[e];
    const float* c = cl + e * NCLS;
    float m = c[0]; int mi = 0;
    #pragma unroll
    for (int k = 1; k < NCLS; ++k) { float v = c[k]; if (v > m) { m = v; mi = k; } }

    bool valid = conf > CONF_THR_F;
    float s = valid ? conf * m : 0.0f;           // exact: single f32 mul, no fma
    uint32_t sb = __float_as_uint(s);            // s >= 0 -> bits monotonic
    keys[idx]      = ((uint64_t)sb << 32) | (uint32_t)(0xFFFFFFFFu - (uint32_t)i);
    boxes_cat[idx] = box;
    score[idx]     = s;
    clsidx[idx]    = mi;
    svout[idx]     = valid ? 1u : 0u;
}

// ---------------------------------------------------------------------------
// Kernel B: stable descending rank sort (rank = #keys strictly greater),
// scatter sorted arrays, build valid bitmap (u64 words) per image
// ---------------------------------------------------------------------------
__global__ void rank_kernel(const uint64_t* __restrict__ keys,
                            const float4* __restrict__ boxes_cat,
                            const float* __restrict__ score,
                            const int* __restrict__ clsidx,
                            const uint32_t* __restrict__ sv,
                            float4* __restrict__ sboxes, float* __restrict__ sscore,
                            int* __restrict__ scls, uint32_t* __restrict__ ssv,
                            u64* __restrict__ validbits, int* __restrict__ nvalid)
{
    int b = blockIdx.y;
    int i = blockIdx.x * 256 + threadIdx.x;
    const uint64_t* kb = keys + (size_t)b * NTOT;
    uint64_t mykey = (i < NTOT) ? kb[i] : 0ull;

    __shared__ uint64_t tile[256];
    int rank = 0;
    for (int t0 = 0; t0 < NTOT; t0 += 256) {
        int j = t0 + threadIdx.x;
        tile[threadIdx.x] = (j < NTOT) ? kb[j] : 0ull;   // 0 never > any real key
        __syncthreads();
        #pragma unroll 8
        for (int t = 0; t < 256; ++t) rank += (tile[t] > mykey) ? 1 : 0;
        __syncthreads();
    }

    if (i < NTOT) {
        size_t src = (size_t)b * NTOT + i;
        size_t dst = (size_t)b * NTOT + rank;
        sboxes[dst] = boxes_cat[src];
        sscore[dst] = score[src];
        scls[dst]   = clsidx[src];
        uint32_t v  = sv[src];
        ssv[dst]    = v;
        if (v) {
            atomicOr(&validbits[(size_t)b * NW64 + (rank >> 6)], 1ull << (rank & 63));
            atomicMax(&nvalid[b], rank + 1);
        }
    }
}

// ---------------------------------------------------------------------------
// Kernel C1 (fast path): build suppression bit-matrix + compact diag blocks
// + super-diagonal blocks (exactly the proven R2-era version).
// mask[(b*NTOT + i)*NW64 + c] = 64-bit word: bit k set iff IoU(i, c*64+k)>thr
// and (c*64+k) > i. Only upper-triangle chunks (c >= r) are written.
// diag [(b*NW64 + g)*64 + lane] = mask word of row g*64+lane at column-chunk g
// sdiag[(b*NW64 + g)*64 + lane] = mask word of row g*64+lane at column-chunk g+1
// ---------------------------------------------------------------------------
__global__ void __launch_bounds__(256) mask_build(const float4* __restrict__ sboxes,
                                                  u64* __restrict__ mask,
                                                  u64* __restrict__ diag,
                                                  u64* __restrict__ sdiag)
{
#pragma clang fp contract(off)
    int c = blockIdx.y;
    if (c < blockIdx.x * 4) return;              // whole block below diagonal
    int b = blockIdx.z;
    int sub = threadIdx.x >> 6;
    int lane = threadIdx.x & 63;
    int r = blockIdx.x * 4 + sub;

    __shared__ float4 cb[64];
    __shared__ float  ca[64];
    if (threadIdx.x < 64) {
        int j = c * 64 + threadIdx.x;
        float4 bj = sboxes[(size_t)b * NTOT + (j < NTOT ? j : NTOT - 1)];
        cb[threadIdx.x] = bj;
        ca[threadIdx.x] = (bj.z - bj.x) * (bj.w - bj.y);
    }
    __syncthreads();

    if (r >= NW64 || c < r) return;              // wave below diagonal / OOB
    int i = r * 64 + lane;
    float4 bi = sboxes[(size_t)b * NTOT + (i < NTOT ? i : NTOT - 1)];
    float ax1 = bi.x, ay1 = bi.y, ax2 = bi.z, ay2 = bi.w;
    float area_i = (ax2 - ax1) * (ay2 - ay1);

    u64 m = 0;
    #pragma unroll 8
    for (int k = 0; k < 64; ++k) {
        float4 bj = cb[k];
        float xx1 = fmaxf(bj.x, ax1);
        float yy1 = fmaxf(bj.y, ay1);
        float xx2 = fminf(bj.z, ax2);
        float yy2 = fminf(bj.w, ay2);
        float w = fmaxf(xx2 - xx1, 0.0f);
        float h = fmaxf(yy2 - yy1, 0.0f);
        float inter = w * h;
        float iou = inter / ((area_i + ca[k]) - inter);   // matches ref op order
        bool set = (iou > IOU_THR_F) && (c > r || k > lane) && (c * 64 + k < NTOT);
        m |= (u64)set << k;
    }
    if (i < NTOT) {
        mask[((size_t)b * NTOT + i) * NW64 + c] = m;
        if (c == r)     diag [((size_t)b * NW64 + r) * 64 + lane] = m;
        if (c == r + 1) sdiag[((size_t)b * NW64 + r) * 64 + lane] = m;
    }
}

// ---------------------------------------------------------------------------
// Kernel C2 (fast path): greedy resolve = the proven R1 structure (bpermute
// chain untouched) with its two measured per-group overheads removed:
//  * far row-OR (words >= g+2): loads issued this group, committed NEXT group
//    (a full group of slack; nothing waits on a just-issued load).
//  * near word g+1: wave 0's kept lanes do one same-address LDS atomicOr of
//    their super-diagonal word (~50cy) -- no 2nd shfl in the chain (R2's
//    mistake), no global round-trip (R1's cost).
//  * klist written redundantly by EVERY wave (identical values; in-wave LDS
//    ordering covers read-back) -> single barrier per group.
// In-group suppressed bits committed by lane 0 (benign race: pre-removing
// suppressed boxes from alive does not change the greedy kept set).
// ---------------------------------------------------------------------------
static __device__ __forceinline__ void bar_sync()
{
    asm volatile("s_waitcnt lgkmcnt(0)" ::: "memory");
    __builtin_amdgcn_s_barrier();
    asm volatile("" ::: "memory");
}

__global__ void __launch_bounds__(1024) resolve_kernel(const u64* __restrict__ mask,
                                                       const u64* __restrict__ diag,
                                                       const u64* __restrict__ sdiag,
                                                       const u64* __restrict__ validbits,
                                                       u64* __restrict__ rem_out)
{
    int b = blockIdx.x;
    int tid = threadIdx.x;
    int lane = tid & 63;
    int wv = tid >> 6;
    const u64* M  = mask  + (size_t)b * NTOT * NW64;
    const u64* D  = diag  + (size_t)b * NW64 * 64;
    const u64* SD = sdiag + (size_t)b * NW64 * 64;
    const u64* V  = validbits + (size_t)b * NW64;

    __shared__ u64 rem_s[NW64 + 1];              // +1 pad absorbs g=last near-OR
    __shared__ u64 v_s[NW64];
    __shared__ int klist[64];

    for (int t = tid; t < NW64; t += 1024) { rem_s[t] = 0ull; v_s[t] = V[t]; }
    if (tid == 0) rem_s[NW64] = 0ull;
    if (tid < 64) klist[tid] = 0;                // safe fallback addresses

    u64 dl  = D[lane];                           // diag word, group 0
    u64 sdl = SD[lane];                          // superdiag word, group 0

    u64 df[4][3];                                // deferred far-OR payload
    #pragma unroll
    for (int t = 0; t < 4; ++t) {
        #pragma unroll
        for (int c = 0; c < 3; ++c) df[t][c] = 0ull;
    }

    bar_sync();

    for (int g = 0; g < NW64; ++g) {
        // 1. alive (LDS; rem_s[g] complete: near-OR at g-1, far-OR at g-1 from g-2)
        u64 alive = v_s[g] & ~rem_s[g];

        // 2. prefetch next group's diag/superdiag (consumed after next barrier;
        //    issued before this group's df so the next chain's wait keeps df in flight)
        int gn = (g + 1 < NW64) ? g + 1 : g;
        u64 dn  = D [(size_t)gn * 64 + lane];
        u64 sdn = SD[(size_t)gn * 64 + lane];

        // 3. THE R1 CHAIN -- unchanged (1 u64 shfl per kept box)
        u64 kept = 0, pend = alive;
        while (pend) {
            int i = __ffsll((unsigned long long)pend) - 1;
            kept |= 1ull << i;
            u64 d = __shfl(dl, i, 64);
            pend &= ~(d | (1ull << i));
        }
        int nk = __popcll(kept);

        // 4. klist (every wave writes identical values -> no barrier needed),
        //    in-group suppressions, near word g+1 via superdiag LDS atomic
        u64 below = (1ull << lane) - 1;
        if ((kept >> lane) & 1)
            klist[__popcll(kept & below)] = lane;
        if (wv == 0) {
            if (lane == 0) {
                u64 supp = alive & ~kept;
                if (supp) atomicOr((unsigned long long*)&rem_s[g], (unsigned long long)supp);
            }
            if (((kept >> lane) & 1) && sdl)
                atomicOr((unsigned long long*)&rem_s[g + 1], (unsigned long long)sdl);
        }

        // 5. commit deferred far-ORs from group g-1 (targets >= g+1; df values
        //    were zero-predicated at issue, so the guard also bounds the index)
        #pragma unroll
        for (int t = 0; t < 4; ++t) {
            #pragma unroll
            for (int c = 0; c < 3; ++c) {
                if (df[t][c])
                    atomicOr((unsigned long long*)&rem_s[g + 1 + (c << 6) + lane],
                             (unsigned long long)df[t][c]);
            }
        }

        // 6. issue this group's far loads (words g+2..166), consumed next group
        #pragma unroll
        for (int t = 0; t < 4; ++t) {
            int s = wv + (t << 4);
            bool has = s < nk;
            int rr = klist[has ? s : 0];
            const u64* R = M + (size_t)(g * 64 + rr) * NW64;
            #pragma unroll
            for (int c = 0; c < 3; ++c) {
                int w = g + 2 + (c << 6) + lane;
                df[t][c] = (has && w < NW64) ? R[w] : 0ull;
            }
        }

        bar_sync();                               // LDS coherent; VMEM in flight
        dl = dn; sdl = sdn;
    }

    for (int t = tid; t < NW64; t += 1024)
        rem_out[(size_t)b * NW64 + t] = rem_s[t];
}

// ---------------------------------------------------------------------------
// Fallback (small ws): original single-block NMS. Writes u32 words into the
// same u64 rem buffer (little-endian layout makes bit positions identical).
// ---------------------------------------------------------------------------
extern __shared__ unsigned char nms_smem[];

__global__ void __launch_bounds__(1024) nms_kernel(const float4* __restrict__ sboxes,
                                                   const uint32_t* __restrict__ ssv,
                                                   const int* __restrict__ nvalid_arr,
                                                   uint32_t* __restrict__ supp_out)
{
#pragma clang fp contract(off)
    int b = blockIdx.x;
    float4*   lbox = (float4*)nms_smem;
    uint32_t* supp = (uint32_t*)(nms_smem + (size_t)LDS_CAP * 16);
    uint32_t* svb  = supp + NW32;

    int nv = nvalid_arr[b];
    const float4* gb = sboxes + (size_t)b * NTOT;
    const uint32_t* gv = ssv + (size_t)b * NTOT;

    for (int t = threadIdx.x; t < NW32; t += 1024) { supp[t] = 0u; svb[t] = 0u; }
    __syncthreads();
    for (int t = threadIdx.x; t < nv; t += 1024) {
        if (t < LDS_CAP) lbox[t] = gb[t];
        if (gv[t]) atomicOr(&svb[t >> 5], 1u << (t & 31));
    }
    __syncthreads();

    for (int i = 0; i < nv; ++i) {
        uint32_t sw = supp[i >> 5];
        if ((sw >> (i & 31)) & 1u) continue;
        uint32_t vw = svb[i >> 5];
        if (!((vw >> (i & 31)) & 1u)) continue;

        float4 bi = (i < LDS_CAP) ? lbox[i] : gb[i];
        float ax1 = bi.x, ay1 = bi.y, ax2 = bi.z, ay2 = bi.w;
        float area_i = (ax2 - ax1) * (ay2 - ay1);

        for (int j = i + 1 + (int)threadIdx.x; j < nv; j += 1024) {
            float4 bj = (j < LDS_CAP) ? lbox[j] : gb[j];
            float xx1 = fmaxf(bj.x, ax1);
            float yy1 = fmaxf(bj.y, ay1);
            float xx2 = fminf(bj.z, ax2);
            float yy2 = fminf(bj.w, ay2);
            float w = fmaxf(xx2 - xx1, 0.0f);
            float h = fmaxf(yy2 - yy1, 0.0f);
            float inter  = w * h;
            float area_j = (bj.z - bj.x) * (bj.w - bj.y);
            float iou = inter / ((area_i + area_j) - inter);
            if (iou > IOU_THR_F) atomicOr(&supp[j >> 5], 1u << (j & 31));
        }
        __syncthreads();
    }

    __syncthreads();
    // u64 layout: u32 word w of image b lives at u32-index b*(2*NW64) + w
    for (int t = threadIdx.x; t < NW32; t += 1024)
        supp_out[(size_t)b * (2 * NW64) + t] = supp[t];
}

// ---------------------------------------------------------------------------
// Kernel D: assemble outputs: dets [B,N,6] then keep [B,N] (as 0/1 floats)
// ---------------------------------------------------------------------------
__global__ void out_kernel(const float4* __restrict__ sboxes, const float* __restrict__ sscore,
                           const int* __restrict__ scls, const uint32_t* __restrict__ ssv,
                           const u64* __restrict__ rem, float* __restrict__ out)
{
    int idx = blockIdx.x * 256 + threadIdx.x;
    if (idx >= NBATCH * NTOT) return;
    int b = idx / NTOT;
    int p = idx - b * NTOT;

    float4 box = sboxes[idx];
    u64 rw = rem[(size_t)b * NW64 + (p >> 6)];
    bool keep = (ssv[idx] != 0u) && !((rw >> (p & 63)) & 1ull);
    float sc = keep ? sscore[idx] : 0.0f;

    float* d = out + (size_t)idx * 6;
    d[0] = box.x; d[1] = box.y; d[2] = box.z; d[3] = box.w;
    d[4] = sc;    d[5] = (float)scls[idx];
    out[(size_t)NBATCH * NTOT * 6 + idx] = keep ? 1.0f : 0.0f;
}

// ---------------------------------------------------------------------------
extern "C" void kernel_launch(void* const* d_in, const int* in_sizes, int n_in,
                              void* d_out, int out_size, void* d_ws, size_t ws_size,
                              hipStream_t stream)
{
    const float* p3b = (const float*)d_in[0];
    const float* p3c = (const float*)d_in[1];
    const float* p3k = (const float*)d_in[2];
    const float* p4b = (const float*)d_in[3];
    const float* p4c = (const float*)d_in[4];
    const float* p4k = (const float*)d_in[5];
    const float* p5b = (const float*)d_in[6];
    const float* p5c = (const float*)d_in[7];
    const float* p5k = (const float*)d_in[8];
    float* out = (float*)d_out;

    // workspace carve-up (256B aligned slabs)
    char* ws = (char*)d_ws;
    size_t off = 0;
    auto alloc = [&](size_t bytes) { size_t o = off; off += (bytes + 255) & ~(size_t)255; return o; };
    const size_t BN = (size_t)NBATCH * NTOT;
    uint64_t* keys      = (uint64_t*)(ws + alloc(BN * 8));
    float4*   boxes_cat = (float4*)  (ws + alloc(BN * 16));
    float*    score     = (float*)   (ws + alloc(BN * 4));
    int*      clsidx    = (int*)     (ws + alloc(BN * 4));
    uint32_t* sv        = (uint32_t*)(ws + alloc(BN * 4));
    float4*   sboxes    = (float4*)  (ws + alloc(BN * 16));
    float*    sscore    = (float*)   (ws + alloc(BN * 4));
    int*      scls      = (int*)     (ws + alloc(BN * 4));
    uint32_t* ssv       = (uint32_t*)(ws + alloc(BN * 4));
    u64*      rem64     = (u64*)     (ws + alloc((size_t)NBATCH * NW64 * 8));
    u64*      validbits = (u64*)     (ws + alloc((size_t)NBATCH * NW64 * 8));
    int*      nvalid    = (int*)     (ws + alloc(NBATCH * 4));
    u64*      diag      = (u64*)     (ws + alloc((size_t)NBATCH * NW64 * 64 * 8));
    u64*      sdiag     = (u64*)     (ws + alloc((size_t)NBATCH * NW64 * 64 * 8));
    u64*      mask      = (u64*)     (ws + alloc((size_t)NBATCH * NTOT * NW64 * 8));
    bool fast = (off <= ws_size);

    hipMemsetAsync(nvalid, 0, NBATCH * 4, stream);
    hipMemsetAsync(validbits, 0, (size_t)NBATCH * NW64 * 8, stream);

    int nblk = (int)((BN + 255) / 256);
    prep_kernel<<<nblk, 256, 0, stream>>>(p3b, p3c, p3k, p4b, p4c, p4k, p5b, p5c, p5k,
                                          keys, boxes_cat, score, clsidx, sv);

    dim3 rgrid((NTOT + 255) / 256, NBATCH);
    rank_kernel<<<rgrid, 256, 0, stream>>>(keys, boxes_cat, score, clsidx, sv,
                                           sboxes, sscore, scls, ssv, validbits, nvalid);

    if (fast) {
        dim3 mgrid((NW64 + 3) / 4, NW64, NBATCH);
        mask_build<<<mgrid, 256, 0, stream>>>(sboxes, mask, diag, sdiag);
        resolve_kernel<<<NBATCH, 1024, 0, stream>>>(mask, diag, sdiag, validbits, rem64);
    } else {
        hipMemsetAsync(rem64, 0, (size_t)NBATCH * NW64 * 8, stream);
        size_t smem = (size_t)LDS_CAP * 16 + (size_t)NW32 * 4 * 2;
        smem = (smem + 15) & ~(size_t)15;
        hipFuncSetAttribute((const void*)nms_kernel, hipFuncAttributeMaxDynamicSharedMemorySize, (int)smem);
        nms_kernel<<<NBATCH, 1024, smem, stream>>>(sboxes, ssv, nvalid, (uint32_t*)rem64);
    }

    out_kernel<<<nblk, 256, 0, stream>>>(sboxes, sscore, scls, ssv, rem64, out);
}

// Round 8
// 739.007 us; speedup vs baseline: 1.5859x; 1.3213x over previous
//
#include <hip/hip_runtime.h>
#include <stdint.h>

#define NB3 8112
#define NB4 2028
#define NB5 507
#define NTOT 10647           // 8112 + 2028 + 507
#define NBATCH 4
#define NCLS 20
#define NW32 333             // ceil(10647 / 32)
#define NW64 167             // ceil(10647 / 64)
#define LDS_CAP 9984         // boxes staged in LDS (fallback kernel)
#define CONF_THR_F 0.1f
#define IOU_THR_F 0.45f

typedef unsigned long long u64;

// ---------------------------------------------------------------------------
// Kernel A: per-box score / class argmax / sort key
// ---------------------------------------------------------------------------
__global__ void prep_kernel(const float* __restrict__ p3b, const float* __restrict__ p3c, const float* __restrict__ p3k,
                            const float* __restrict__ p4b, const float* __restrict__ p4c, const float* __restrict__ p4k,
                            const float* __restrict__ p5b, const float* __restrict__ p5c, const float* __restrict__ p5k,
                            uint64_t* __restrict__ keys, float4* __restrict__ boxes_cat,
                            float* __restrict__ score, int* __restrict__ clsidx, uint32_t* __restrict__ svout)
{
#pragma clang fp contract(off)
    int idx = blockIdx.x * 256 + threadIdx.x;
    if (idx >= NBATCH * NTOT) return;
    int b = idx / NTOT;
    int i = idx - b * NTOT;

    const float* bx; const float* cf; const float* cl; int n, off;
    if (i < NB3)            { bx = p3b; cf = p3c; cl = p3k; n = NB3; off = i; }
    else if (i < NB3 + NB4) { bx = p4b; cf = p4c; cl = p4k; n = NB4; off = i - NB3; }
    else                    { bx = p5b; cf = p5c; cl = p5k; n = NB5; off = i - NB3 - NB4; }

    size_t e = (size_t)b * n + off;
    float4 box = *(const float4*)(bx + e * 4);
    float conf = cf[e];
    const float* c = cl + e * NCLS;
    float m = c[0]; int mi = 0;
    #pragma unroll
    for (int k = 1; k < NCLS; ++k) { float v = c[k]; if (v > m) { m = v; mi = k; } }

    bool valid = conf > CONF_THR_F;
    float s = valid ? conf * m : 0.0f;           // exact: single f32 mul, no fma
    uint32_t sb = __float_as_uint(s);            // s >= 0 -> bits monotonic
    keys[idx]      = ((uint64_t)sb << 32) | (uint32_t)(0xFFFFFFFFu - (uint32_t)i);
    boxes_cat[idx] = box;
    score[idx]     = s;
    clsidx[idx]    = mi;
    svout[idx]     = valid ? 1u : 0u;
}

// ---------------------------------------------------------------------------
// Kernel B: stable descending rank sort (rank = #keys strictly greater),
// scatter sorted arrays, build valid bitmap (u64 words) per image
// ---------------------------------------------------------------------------
__global__ void rank_kernel(const uint64_t* __restrict__ keys,
                            const float4* __restrict__ boxes_cat,
                            const float* __restrict__ score,
                            const int* __restrict__ clsidx,
                            const uint32_t* __restrict__ sv,
                            float4* __restrict__ sboxes, float* __restrict__ sscore,
                            int* __restrict__ scls, uint32_t* __restrict__ ssv,
                            u64* __restrict__ validbits, int* __restrict__ nvalid)
{
    int b = blockIdx.y;
    int i = blockIdx.x * 256 + threadIdx.x;
    const uint64_t* kb = keys + (size_t)b * NTOT;
    uint64_t mykey = (i < NTOT) ? kb[i] : 0ull;

    __shared__ uint64_t tile[256];
    int rank = 0;
    for (int t0 = 0; t0 < NTOT; t0 += 256) {
        int j = t0 + threadIdx.x;
        tile[threadIdx.x] = (j < NTOT) ? kb[j] : 0ull;   // 0 never > any real key
        __syncthreads();
        #pragma unroll 8
        for (int t = 0; t < 256; ++t) rank += (tile[t] > mykey) ? 1 : 0;
        __syncthreads();
    }

    if (i < NTOT) {
        size_t src = (size_t)b * NTOT + i;
        size_t dst = (size_t)b * NTOT + rank;
        sboxes[dst] = boxes_cat[src];
        sscore[dst] = score[src];
        scls[dst]   = clsidx[src];
        uint32_t v  = sv[src];
        ssv[dst]    = v;
        if (v) {
            atomicOr(&validbits[(size_t)b * NW64 + (rank >> 6)], 1ull << (rank & 63));
            atomicMax(&nvalid[b], rank + 1);
        }
    }
}

// ---------------------------------------------------------------------------
// Kernel C1 (fast path): build suppression bit-matrix + compact diag blocks
// + super-diagonal blocks (unchanged, proven).
// mask[(b*NTOT + i)*NW64 + c] = 64-bit word: bit k set iff IoU(i, c*64+k)>thr
// and (c*64+k) > i. Only upper-triangle chunks (c >= r) are written.
// diag [(b*NW64 + g)*64 + lane] = mask word of row g*64+lane at column-chunk g
// sdiag[(b*NW64 + g)*64 + lane] = mask word of row g*64+lane at column-chunk g+1
// ---------------------------------------------------------------------------
__global__ void __launch_bounds__(256) mask_build(const float4* __restrict__ sboxes,
                                                  u64* __restrict__ mask,
                                                  u64* __restrict__ diag,
                                                  u64* __restrict__ sdiag)
{
#pragma clang fp contract(off)
    int c = blockIdx.y;
    if (c < blockIdx.x * 4) return;              // whole block below diagonal
    int b = blockIdx.z;
    int sub = threadIdx.x >> 6;
    int lane = threadIdx.x & 63;
    int r = blockIdx.x * 4 + sub;

    __shared__ float4 cb[64];
    __shared__ float  ca[64];
    if (threadIdx.x < 64) {
        int j = c * 64 + threadIdx.x;
        float4 bj = sboxes[(size_t)b * NTOT + (j < NTOT ? j : NTOT - 1)];
        cb[threadIdx.x] = bj;
        ca[threadIdx.x] = (bj.z - bj.x) * (bj.w - bj.y);
    }
    __syncthreads();

    if (r >= NW64 || c < r) return;              // wave below diagonal / OOB
    int i = r * 64 + lane;
    float4 bi = sboxes[(size_t)b * NTOT + (i < NTOT ? i : NTOT - 1)];
    float ax1 = bi.x, ay1 = bi.y, ax2 = bi.z, ay2 = bi.w;
    float area_i = (ax2 - ax1) * (ay2 - ay1);

    u64 m = 0;
    #pragma unroll 8
    for (int k = 0; k < 64; ++k) {
        float4 bj = cb[k];
        float xx1 = fmaxf(bj.x, ax1);
        float yy1 = fmaxf(bj.y, ay1);
        float xx2 = fminf(bj.z, ax2);
        float yy2 = fminf(bj.w, ay2);
        float w = fmaxf(xx2 - xx1, 0.0f);
        float h = fmaxf(yy2 - yy1, 0.0f);
        float inter = w * h;
        float iou = inter / ((area_i + ca[k]) - inter);   // matches ref op order
        bool set = (iou > IOU_THR_F) && (c > r || k > lane) && (c * 64 + k < NTOT);
        m |= (u64)set << k;
    }
    if (i < NTOT) {
        mask[((size_t)b * NTOT + i) * NW64 + c] = m;
        if (c == r)     diag [((size_t)b * NW64 + r) * 64 + lane] = m;
        if (c == r + 1) sdiag[((size_t)b * NW64 + r) * 64 + lane] = m;
    }
}

// ---------------------------------------------------------------------------
// Kernel C2 (fast path): greedy resolve. R7's schedule, but the serial chain
// runs in ONE wave as a pure scalar readlane chain (~5 ops/step, no LDS pipe,
// no 16-wave contention -- the measured cost driver of R1-R4). Waves 1-15
// wait at the barrier (idle waves consume no issue slots) and carry the
// parallel work: deferred far-OR commit (vmcnt stall overlaps wave 0's
// chain) + far-load issue.
// Single barrier per group; kept_s/klist double-buffered by parity so the
// one-barrier schedule is race-free (wave 0 at group g+1 writes buffer
// (g+1)&1 while a slow wave still reads buffer g&1).
// ---------------------------------------------------------------------------
static __device__ __forceinline__ void bar_sync()
{
    asm volatile("s_waitcnt lgkmcnt(0)" ::: "memory");
    __builtin_amdgcn_s_barrier();
    asm volatile("" ::: "memory");
}

static __device__ __forceinline__ u64 rfl64(u64 x)
{
    uint32_t lo = __builtin_amdgcn_readfirstlane((uint32_t)x);
    uint32_t hi = __builtin_amdgcn_readfirstlane((uint32_t)(x >> 32));
    return ((u64)hi << 32) | (u64)lo;
}

static __device__ __forceinline__ u64 rl64(u64 x, int lane)
{
    uint32_t lo = (uint32_t)__builtin_amdgcn_readlane((int)(uint32_t)x, lane);
    uint32_t hi = (uint32_t)__builtin_amdgcn_readlane((int)(uint32_t)(x >> 32), lane);
    return ((u64)hi << 32) | (u64)lo;
}

__global__ void __launch_bounds__(1024) resolve_kernel(const u64* __restrict__ mask,
                                                       const u64* __restrict__ diag,
                                                       const u64* __restrict__ sdiag,
                                                       const u64* __restrict__ validbits,
                                                       u64* __restrict__ rem_out)
{
    int b = blockIdx.x;
    int tid = threadIdx.x;
    int lane = tid & 63;
    int wv = tid >> 6;
    const u64* M  = mask  + (size_t)b * NTOT * NW64;
    const u64* D  = diag  + (size_t)b * NW64 * 64;
    const u64* SD = sdiag + (size_t)b * NW64 * 64;
    const u64* V  = validbits + (size_t)b * NW64;

    __shared__ u64 rem_s[NW64 + 1];              // +1 pad absorbs g=last near-OR
    __shared__ u64 v_s[NW64];
    __shared__ u64 kept_s[2];                    // parity double-buffered
    __shared__ int klist[2][64];

    for (int t = tid; t < NW64; t += 1024) { rem_s[t] = 0ull; v_s[t] = V[t]; }
    if (tid == 0) { rem_s[NW64] = 0ull; kept_s[0] = 0ull; kept_s[1] = 0ull;
                    klist[0][0] = 0; klist[1][0] = 0; }

    u64 dl = 0, sdl = 0;
    if (wv == 0) { dl = D[lane]; sdl = SD[lane]; }   // wave 0 only

    u64 df[4][3];                                // deferred far-OR payload
    #pragma unroll
    for (int t = 0; t < 4; ++t) {
        #pragma unroll
        for (int c = 0; c < 3; ++c) df[t][c] = 0ull;
    }

    bar_sync();

    for (int g = 0; g < NW64; ++g) {
        int par = g & 1;

        // ---- section A (before barrier) ----
        if (wv == 0) {
            // scalar readlane chain: s_ff1 -> 2x v_readlane -> s_andn2 per step
            u64 alive = v_s[g] & ~rem_s[g];
            u64 pend = rfl64(alive);
            u64 kept = 0;
            while (pend) {
                int i = __ffsll((unsigned long long)pend) - 1;
                u64 bit = 1ull << i;
                kept |= bit;
                u64 d = rl64(dl, i);
                pend &= ~(d | bit);
            }
            if (lane == 0) {
                kept_s[par] = kept;
                u64 supp = pend = rfl64(alive) & ~kept;   // in-group suppressed
                if (supp) atomicOr((unsigned long long*)&rem_s[g], (unsigned long long)supp);
            }
            // near word g+1: kept lanes OR their superdiag word (same-addr LDS atomic)
            if (((kept >> lane) & 1) && sdl)
                atomicOr((unsigned long long*)&rem_s[g + 1], (unsigned long long)sdl);
            // prefetch next diag/sdiag (consumed at next group's chain)
            int gn = (g + 1 < NW64) ? g + 1 : g;
            u64 dn  = D [(size_t)gn * 64 + lane];
            u64 sdn = SD[(size_t)gn * 64 + lane];
            dl = dn; sdl = sdn;
        }
        // all waves: commit deferred far-ORs from group g-1 (targets >= g+1).
        // For waves 1-15 the vmcnt stall here overlaps wave 0's chain.
        #pragma unroll
        for (int t = 0; t < 4; ++t) {
            #pragma unroll
            for (int c = 0; c < 3; ++c) {
                if (df[t][c])
                    atomicOr((unsigned long long*)&rem_s[g + 1 + (c << 6) + lane],
                             (unsigned long long)df[t][c]);
            }
        }

        bar_sync();                               // kept_s/rem_s[g+1] final

        // ---- section B (after barrier): broadcast + far-load issue ----
        u64 kept = kept_s[par];
        int nk = __popcll(kept);
        u64 below = (1ull << lane) - 1;
        if ((kept >> lane) & 1)
            klist[par][__popcll(kept & below)] = lane;   // redundant per wave
        #pragma unroll
        for (int t = 0; t < 4; ++t) {
            int s = wv + (t << 4);
            bool has = s < nk;
            int rr = klist[par][has ? s : 0];
            const u64* R = M + (size_t)(g * 64 + rr) * NW64;
            #pragma unroll
            for (int c = 0; c < 3; ++c) {
                int w = g + 2 + (c << 6) + lane;
                df[t][c] = (has && w < NW64) ? R[w] : 0ull;
            }
        }
        // no second barrier: next group's A only touches rem_s (finalized
        // above) and the opposite-parity kept_s/klist buffers.
    }

    for (int t = tid; t < NW64; t += 1024)
        rem_out[(size_t)b * NW64 + t] = rem_s[t];
}

// ---------------------------------------------------------------------------
// Fallback (small ws): original single-block NMS. Writes u32 words into the
// same u64 rem buffer (little-endian layout makes bit positions identical).
// ---------------------------------------------------------------------------
extern __shared__ unsigned char nms_smem[];

__global__ void __launch_bounds__(1024) nms_kernel(const float4* __restrict__ sboxes,
                                                   const uint32_t* __restrict__ ssv,
                                                   const int* __restrict__ nvalid_arr,
                                                   uint32_t* __restrict__ supp_out)
{
#pragma clang fp contract(off)
    int b = blockIdx.x;
    float4*   lbox = (float4*)nms_smem;
    uint32_t* supp = (uint32_t*)(nms_smem + (size_t)LDS_CAP * 16);
    uint32_t* svb  = supp + NW32;

    int nv = nvalid_arr[b];
    const float4* gb = sboxes + (size_t)b * NTOT;
    const uint32_t* gv = ssv + (size_t)b * NTOT;

    for (int t = threadIdx.x; t < NW32; t += 1024) { supp[t] = 0u; svb[t] = 0u; }
    __syncthreads();
    for (int t = threadIdx.x; t < nv; t += 1024) {
        if (t < LDS_CAP) lbox[t] = gb[t];
        if (gv[t]) atomicOr(&svb[t >> 5], 1u << (t & 31));
    }
    __syncthreads();

    for (int i = 0; i < nv; ++i) {
        uint32_t sw = supp[i >> 5];
        if ((sw >> (i & 31)) & 1u) continue;
        uint32_t vw = svb[i >> 5];
        if (!((vw >> (i & 31)) & 1u)) continue;

        float4 bi = (i < LDS_CAP) ? lbox[i] : gb[i];
        float ax1 = bi.x, ay1 = bi.y, ax2 = bi.z, ay2 = bi.w;
        float area_i = (ax2 - ax1) * (ay2 - ay1);

        for (int j = i + 1 + (int)threadIdx.x; j < nv; j += 1024) {
            float4 bj = (j < LDS_CAP) ? lbox[j] : gb[j];
            float xx1 = fmaxf(bj.x, ax1);
            float yy1 = fmaxf(bj.y, ay1);
            float xx2 = fminf(bj.z, ax2);
            float yy2 = fminf(bj.w, ay2);
            float w = fmaxf(xx2 - xx1, 0.0f);
            float h = fmaxf(yy2 - yy1, 0.0f);
            float inter  = w * h;
            float area_j = (bj.z - bj.x) * (bj.w - bj.y);
            float iou = inter / ((area_i + area_j) - inter);
            if (iou > IOU_THR_F) atomicOr(&supp[j >> 5], 1u << (j & 31));
        }
        __syncthreads();
    }

    __syncthreads();
    // u64 layout: u32 word w of image b lives at u32-index b*(2*NW64) + w
    for (int t = threadIdx.x; t < NW32; t += 1024)
        supp_out[(size_t)b * (2 * NW64) + t] = supp[t];
}

// ---------------------------------------------------------------------------
// Kernel D: assemble outputs: dets [B,N,6] then keep [B,N] (as 0/1 floats)
// ---------------------------------------------------------------------------
__global__ void out_kernel(const float4* __restrict__ sboxes, const float* __restrict__ sscore,
                           const int* __restrict__ scls, const uint32_t* __restrict__ ssv,
                           const u64* __restrict__ rem, float* __restrict__ out)
{
    int idx = blockIdx.x * 256 + threadIdx.x;
    if (idx >= NBATCH * NTOT) return;
    int b = idx / NTOT;
    int p = idx - b * NTOT;

    float4 box = sboxes[idx];
    u64 rw = rem[(size_t)b * NW64 + (p >> 6)];
    bool keep = (ssv[idx] != 0u) && !((rw >> (p & 63)) & 1ull);
    float sc = keep ? sscore[idx] : 0.0f;

    float* d = out + (size_t)idx * 6;
    d[0] = box.x; d[1] = box.y; d[2] = box.z; d[3] = box.w;
    d[4] = sc;    d[5] = (float)scls[idx];
    out[(size_t)NBATCH * NTOT * 6 + idx] = keep ? 1.0f : 0.0f;
}

// ---------------------------------------------------------------------------
extern "C" void kernel_launch(void* const* d_in, const int* in_sizes, int n_in,
                              void* d_out, int out_size, void* d_ws, size_t ws_size,
                              hipStream_t stream)
{
    const float* p3b = (const float*)d_in[0];
    const float* p3c = (const float*)d_in[1];
    const float* p3k = (const float*)d_in[2];
    const float* p4b = (const float*)d_in[3];
    const float* p4c = (const float*)d_in[4];
    const float* p4k = (const float*)d_in[5];
    const float* p5b = (const float*)d_in[6];
    const float* p5c = (const float*)d_in[7];
    const float* p5k = (const float*)d_in[8];
    float* out = (float*)d_out;

    // workspace carve-up (256B aligned slabs)
    char* ws = (char*)d_ws;
    size_t off = 0;
    auto alloc = [&](size_t bytes) { size_t o = off; off += (bytes + 255) & ~(size_t)255; return o; };
    const size_t BN = (size_t)NBATCH * NTOT;
    uint64_t* keys      = (uint64_t*)(ws + alloc(BN * 8));
    float4*   boxes_cat = (float4*)  (ws + alloc(BN * 16));
    float*    score     = (float*)   (ws + alloc(BN * 4));
    int*      clsidx    = (int*)     (ws + alloc(BN * 4));
    uint32_t* sv        = (uint32_t*)(ws + alloc(BN * 4));
    float4*   sboxes    = (float4*)  (ws + alloc(BN * 16));
    float*    sscore    = (float*)   (ws + alloc(BN * 4));
    int*      scls      = (int*)     (ws + alloc(BN * 4));
    uint32_t* ssv       = (uint32_t*)(ws + alloc(BN * 4));
    u64*      rem64     = (u64*)     (ws + alloc((size_t)NBATCH * NW64 * 8));
    u64*      validbits = (u64*)     (ws + alloc((size_t)NBATCH * NW64 * 8));
    int*      nvalid    = (int*)     (ws + alloc(NBATCH * 4));
    u64*      diag      = (u64*)     (ws + alloc((size_t)NBATCH * NW64 * 64 * 8));
    u64*      sdiag     = (u64*)     (ws + alloc((size_t)NBATCH * NW64 * 64 * 8));
    u64*      mask      = (u64*)     (ws + alloc((size_t)NBATCH * NTOT * NW64 * 8));
    bool fast = (off <= ws_size);

    hipMemsetAsync(nvalid, 0, NBATCH * 4, stream);
    hipMemsetAsync(validbits, 0, (size_t)NBATCH * NW64 * 8, stream);

    int nblk = (int)((BN + 255) / 256);
    prep_kernel<<<nblk, 256, 0, stream>>>(p3b, p3c, p3k, p4b, p4c, p4k, p5b, p5c, p5k,
                                          keys, boxes_cat, score, clsidx, sv);

    dim3 rgrid((NTOT + 255) / 256, NBATCH);
    rank_kernel<<<rgrid, 256, 0, stream>>>(keys, boxes_cat, score, clsidx, sv,
                                           sboxes, sscore, scls, ssv, validbits, nvalid);

    if (fast) {
        dim3 mgrid((NW64 + 3) / 4, NW64, NBATCH);
        mask_build<<<mgrid, 256, 0, stream>>>(sboxes, mask, diag, sdiag);
        resolve_kernel<<<NBATCH, 1024, 0, stream>>>(mask, diag, sdiag, validbits, rem64);
    } else {
        hipMemsetAsync(rem64, 0, (size_t)NBATCH * NW64 * 8, stream);
        size_t smem = (size_t)LDS_CAP * 16 + (size_t)NW32 * 4 * 2;
        smem = (smem + 15) & ~(size_t)15;
        hipFuncSetAttribute((const void*)nms_kernel, hipFuncAttributeMaxDynamicSharedMemorySize, (int)smem);
        nms_kernel<<<NBATCH, 1024, smem, stream>>>(sboxes, ssv, nvalid, (uint32_t*)rem64);
    }

    out_kernel<<<nblk, 256, 0, stream>>>(sboxes, sscore, scls, ssv, rem64, out);
}

// Round 9
// 705.639 us; speedup vs baseline: 1.6609x; 1.0473x over previous
//
#include <hip/hip_runtime.h>
#include <stdint.h>

#define NB3 8112
#define NB4 2028
#define NB5 507
#define NTOT 10647           // 8112 + 2028 + 507
#define NBATCH 4
#define NCLS 20
#define NW32 333             // ceil(10647 / 32)
#define NW64 167             // ceil(10647 / 64)
#define NPAIR 84             // ceil(NW64 / 2): 128-box groups for resolve
#define LDS_CAP 9984         // boxes staged in LDS (fallback kernel)
#define CONF_THR_F 0.1f
#define IOU_THR_F 0.45f

typedef unsigned long long u64;

// ---------------------------------------------------------------------------
// Kernel A: per-box score / class argmax / sort key
// ---------------------------------------------------------------------------
__global__ void prep_kernel(const float* __restrict__ p3b, const float* __restrict__ p3c, const float* __restrict__ p3k,
                            const float* __restrict__ p4b, const float* __restrict__ p4c, const float* __restrict__ p4k,
                            const float* __restrict__ p5b, const float* __restrict__ p5c, const float* __restrict__ p5k,
                            uint64_t* __restrict__ keys, float4* __restrict__ boxes_cat,
                            float* __restrict__ score, int* __restrict__ clsidx, uint32_t* __restrict__ svout)
{
#pragma clang fp contract(off)
    int idx = blockIdx.x * 256 + threadIdx.x;
    if (idx >= NBATCH * NTOT) return;
    int b = idx / NTOT;
    int i = idx - b * NTOT;

    const float* bx; const float* cf; const float* cl; int n, off;
    if (i < NB3)            { bx = p3b; cf = p3c; cl = p3k; n = NB3; off = i; }
    else if (i < NB3 + NB4) { bx = p4b; cf = p4c; cl = p4k; n = NB4; off = i - NB3; }
    else                    { bx = p5b; cf = p5c; cl = p5k; n = NB5; off = i - NB3 - NB4; }

    size_t e = (size_t)b * n + off;
    float4 box = *(const float4*)(bx + e * 4);
    float conf = cf[e];
    const float* c = cl + e * NCLS;
    float m = c[0]; int mi = 0;
    #pragma unroll
    for (int k = 1; k < NCLS; ++k) { float v = c[k]; if (v > m) { m = v; mi = k; } }

    bool valid = conf > CONF_THR_F;
    float s = valid ? conf * m : 0.0f;           // exact: single f32 mul, no fma
    uint32_t sb = __float_as_uint(s);            // s >= 0 -> bits monotonic
    keys[idx]      = ((uint64_t)sb << 32) | (uint32_t)(0xFFFFFFFFu - (uint32_t)i);
    boxes_cat[idx] = box;
    score[idx]     = s;
    clsidx[idx]    = mi;
    svout[idx]     = valid ? 1u : 0u;
}

// ---------------------------------------------------------------------------
// Kernel B: stable descending rank sort (rank = #keys strictly greater),
// scatter sorted arrays, build valid bitmap (u64 words) per image
// ---------------------------------------------------------------------------
__global__ void rank_kernel(const uint64_t* __restrict__ keys,
                            const float4* __restrict__ boxes_cat,
                            const float* __restrict__ score,
                            const int* __restrict__ clsidx,
                            const uint32_t* __restrict__ sv,
                            float4* __restrict__ sboxes, float* __restrict__ sscore,
                            int* __restrict__ scls, uint32_t* __restrict__ ssv,
                            u64* __restrict__ validbits, int* __restrict__ nvalid)
{
    int b = blockIdx.y;
    int i = blockIdx.x * 256 + threadIdx.x;
    const uint64_t* kb = keys + (size_t)b * NTOT;
    uint64_t mykey = (i < NTOT) ? kb[i] : 0ull;

    __shared__ uint64_t tile[256];
    int rank = 0;
    for (int t0 = 0; t0 < NTOT; t0 += 256) {
        int j = t0 + threadIdx.x;
        tile[threadIdx.x] = (j < NTOT) ? kb[j] : 0ull;   // 0 never > any real key
        __syncthreads();
        #pragma unroll 8
        for (int t = 0; t < 256; ++t) rank += (tile[t] > mykey) ? 1 : 0;
        __syncthreads();
    }

    if (i < NTOT) {
        size_t src = (size_t)b * NTOT + i;
        size_t dst = (size_t)b * NTOT + rank;
        sboxes[dst] = boxes_cat[src];
        sscore[dst] = score[src];
        scls[dst]   = clsidx[src];
        uint32_t v  = sv[src];
        ssv[dst]    = v;
        if (v) {
            atomicOr(&validbits[(size_t)b * NW64 + (rank >> 6)], 1ull << (rank & 63));
            atomicMax(&nvalid[b], rank + 1);
        }
    }
}

// ---------------------------------------------------------------------------
// Kernel C1 (fast path): build suppression bit-matrix + band buffers at
// distances 0..3 from the diagonal (coalesced copies for resolve's chain):
// mask[(b*NTOT + i)*NW64 + c] = 64-bit word: bit k set iff IoU(i, c*64+k)>thr
// and (c*64+k) > i. Only upper-triangle chunks (c >= r) are written.
// diag/sdiag/s2diag/s3diag[(b*NW64 + r)*64 + lane] = mask word of row
// r*64+lane at column-chunk r / r+1 / r+2 / r+3 (unwritten when c >= NW64;
// resolve guards every use of those entries by target-word bounds).
// ---------------------------------------------------------------------------
__global__ void __launch_bounds__(256) mask_build(const float4* __restrict__ sboxes,
                                                  u64* __restrict__ mask,
                                                  u64* __restrict__ diag,
                                                  u64* __restrict__ sdiag,
                                                  u64* __restrict__ s2diag,
                                                  u64* __restrict__ s3diag)
{
#pragma clang fp contract(off)
    int c = blockIdx.y;
    if (c < blockIdx.x * 4) return;              // whole block below diagonal
    int b = blockIdx.z;
    int sub = threadIdx.x >> 6;
    int lane = threadIdx.x & 63;
    int r = blockIdx.x * 4 + sub;

    __shared__ float4 cb[64];
    __shared__ float  ca[64];
    if (threadIdx.x < 64) {
        int j = c * 64 + threadIdx.x;
        float4 bj = sboxes[(size_t)b * NTOT + (j < NTOT ? j : NTOT - 1)];
        cb[threadIdx.x] = bj;
        ca[threadIdx.x] = (bj.z - bj.x) * (bj.w - bj.y);
    }
    __syncthreads();

    if (r >= NW64 || c < r) return;              // wave below diagonal / OOB
    int i = r * 64 + lane;
    float4 bi = sboxes[(size_t)b * NTOT + (i < NTOT ? i : NTOT - 1)];
    float ax1 = bi.x, ay1 = bi.y, ax2 = bi.z, ay2 = bi.w;
    float area_i = (ax2 - ax1) * (ay2 - ay1);

    u64 m = 0;
    #pragma unroll 8
    for (int k = 0; k < 64; ++k) {
        float4 bj = cb[k];
        float xx1 = fmaxf(bj.x, ax1);
        float yy1 = fmaxf(bj.y, ay1);
        float xx2 = fminf(bj.z, ax2);
        float yy2 = fminf(bj.w, ay2);
        float w = fmaxf(xx2 - xx1, 0.0f);
        float h = fmaxf(yy2 - yy1, 0.0f);
        float inter = w * h;
        float iou = inter / ((area_i + ca[k]) - inter);   // matches ref op order
        bool set = (iou > IOU_THR_F) && (c > r || k > lane) && (c * 64 + k < NTOT);
        m |= (u64)set << k;
    }
    if (i < NTOT) {
        mask[((size_t)b * NTOT + i) * NW64 + c] = m;
        size_t bl = ((size_t)b * NW64 + r) * 64 + lane;
        if (c == r)     diag  [bl] = m;
        if (c == r + 1) sdiag [bl] = m;
        if (c == r + 2) s2diag[bl] = m;
        if (c == r + 3) s3diag[bl] = m;
    }
}

// ---------------------------------------------------------------------------
// Kernel C2 (fast path): greedy resolve, R8's proven structure (single-wave
// scalar readlane chain, single barrier, parity buffers, deferred far-OR)
// widened to 128-box PAIRS: 84 serial iterations instead of 167 -- the chain
// total is invariant (one step per kept box) but the fixed per-iteration
// overhead (barrier arrival, LDS round-trips, df vmcnt wait) is paid half as
// often. Word0 decisions apply their SD suppressions to word1 before word1's
// ffs loop => exactly greedy order. Near words 2p+2/2p+3 commit from the
// distance-1/2/3 bands; far words (>= 2p+4) keep the deferred df scheme.
// nk>64 (early pairs) handled by a rare immediate second pass in section B.
// ---------------------------------------------------------------------------
static __device__ __forceinline__ void bar_sync()
{
    asm volatile("s_waitcnt lgkmcnt(0)" ::: "memory");
    __builtin_amdgcn_s_barrier();
    asm volatile("" ::: "memory");
}

static __device__ __forceinline__ u64 rfl64(u64 x)
{
    uint32_t lo = __builtin_amdgcn_readfirstlane((uint32_t)x);
    uint32_t hi = __builtin_amdgcn_readfirstlane((uint32_t)(x >> 32));
    return ((u64)hi << 32) | (u64)lo;
}

static __device__ __forceinline__ u64 rl64(u64 x, int lane)
{
    uint32_t lo = (uint32_t)__builtin_amdgcn_readlane((int)(uint32_t)x, lane);
    uint32_t hi = (uint32_t)__builtin_amdgcn_readlane((int)(uint32_t)(x >> 32), lane);
    return ((u64)hi << 32) | (u64)lo;
}

__global__ void __launch_bounds__(1024) resolve_kernel(const u64* __restrict__ mask,
                                                       const u64* __restrict__ diag,
                                                       const u64* __restrict__ sdiag,
                                                       const u64* __restrict__ s2diag,
                                                       const u64* __restrict__ s3diag,
                                                       const u64* __restrict__ validbits,
                                                       u64* __restrict__ rem_out)
{
    int b = blockIdx.x;
    int tid = threadIdx.x;
    int lane = tid & 63;
    int wv = tid >> 6;
    const u64* M  = mask   + (size_t)b * NTOT * NW64;
    const u64* D  = diag   + (size_t)b * NW64 * 64;
    const u64* SD = sdiag  + (size_t)b * NW64 * 64;
    const u64* S2 = s2diag + (size_t)b * NW64 * 64;
    const u64* S3 = s3diag + (size_t)b * NW64 * 64;
    const u64* V  = validbits + (size_t)b * NW64;

    __shared__ u64 rem_s[NW64 + 1];              // +1: word index 167 (pair tail)
    __shared__ u64 v_s[NW64 + 1];                // v_s[167] = 0 -> alive1 = 0
    __shared__ u64 kept_s[2][2];                 // parity double-buffered
    __shared__ int klist[2][128];

    for (int t = tid; t < NW64; t += 1024) { rem_s[t] = 0ull; v_s[t] = V[t]; }
    if (tid == 0) {
        rem_s[NW64] = 0ull; v_s[NW64] = 0ull;
        kept_s[0][0] = kept_s[0][1] = kept_s[1][0] = kept_s[1][1] = 0ull;
        klist[0][0] = 0; klist[1][0] = 0;
    }

    // wave 0's register bands for pair 0 (word0 = 0, word1 = 1)
    u64 dl0 = 0, sd0 = 0, s2_0 = 0, s3_0 = 0, dl1 = 0, s1_1 = 0, s2_1 = 0;
    if (wv == 0) {
        dl0 = D[lane];       sd0 = SD[lane];
        s2_0 = S2[lane];     s3_0 = S3[lane];
        dl1 = D[64 + lane];  s1_1 = SD[64 + lane]; s2_1 = S2[64 + lane];
    }

    u64 df[4][3];                                // deferred far-OR payload
    #pragma unroll
    for (int t = 0; t < 4; ++t) {
        #pragma unroll
        for (int c = 0; c < 3; ++c) df[t][c] = 0ull;
    }

    bar_sync();

    for (int p = 0; p < NPAIR; ++p) {
        int par = p & 1;
        int w0 = 2 * p, w1 = 2 * p + 1;

        // ---- section A (before barrier) ----
        if (wv == 0) {
            u64 alive0 = v_s[w0] & ~rem_s[w0];
            u64 alive1 = v_s[w1] & ~rem_s[w1];   // w1==167 -> v_s pad gives 0
            u64 p0 = rfl64(alive0), p1 = rfl64(alive1);
            u64 a0s = p0, a1s = p1;
            u64 k0 = 0, k1 = 0;
            while (p0) {                          // word0: suppress in-word + word1
                int i = __ffsll((unsigned long long)p0) - 1;
                u64 bit = 1ull << i;
                k0 |= bit;
                p0 &= ~(rl64(dl0, i) | bit);
                p1 &= ~rl64(sd0, i);
            }
            while (p1) {                          // word1: suppress in-word
                int i = __ffsll((unsigned long long)p1) - 1;
                u64 bit = 1ull << i;
                k1 |= bit;
                p1 &= ~(rl64(dl1, i) | bit);
            }
            if (lane == 0) {
                kept_s[par][0] = k0; kept_s[par][1] = k1;
                u64 sup0 = a0s & ~k0;
                u64 sup1 = a1s & ~k1;
                if (sup0) atomicOr((unsigned long long*)&rem_s[w0], (unsigned long long)sup0);
                if (sup1) atomicOr((unsigned long long*)&rem_s[w1], (unsigned long long)sup1);
            }
            // near words w0+2 / w0+3 from register bands (guard by TARGET index;
            // band values are garbage when the source column chunk >= NW64)
            int w2 = w0 + 2, w3 = w0 + 3;
            bool h2 = w2 < NW64, h3 = w3 < NW64;
            if ((k0 >> lane) & 1) {
                if (h2 && s2_0) atomicOr((unsigned long long*)&rem_s[w2], (unsigned long long)s2_0);
                if (h3 && s3_0) atomicOr((unsigned long long*)&rem_s[w3], (unsigned long long)s3_0);
            }
            if ((k1 >> lane) & 1) {
                if (h2 && s1_1) atomicOr((unsigned long long*)&rem_s[w2], (unsigned long long)s1_1);
                if (h3 && s2_1) atomicOr((unsigned long long*)&rem_s[w3], (unsigned long long)s2_1);
            }
            // prefetch next pair's bands (consumed after next barrier)
            int pn = (p + 1 < NPAIR) ? p + 1 : p;
            int i0 = 2 * pn;
            int i1 = (2 * pn + 1 < NW64) ? 2 * pn + 1 : NW64 - 1;
            dl0  = D [(size_t)i0 * 64 + lane];
            sd0  = SD[(size_t)i0 * 64 + lane];
            s2_0 = S2[(size_t)i0 * 64 + lane];
            s3_0 = S3[(size_t)i0 * 64 + lane];
            dl1  = D [(size_t)i1 * 64 + lane];
            s1_1 = SD[(size_t)i1 * 64 + lane];
            s2_1 = S2[(size_t)i1 * 64 + lane];
        }
        // all waves: commit deferred far-ORs from pair p-1 (targets >= w0+2;
        // df zero-predicated at issue bounds the index). For waves 1-15 the
        // vmcnt stall here overlaps wave 0's chain.
        #pragma unroll
        for (int t = 0; t < 4; ++t) {
            #pragma unroll
            for (int c = 0; c < 3; ++c) {
                if (df[t][c])
                    atomicOr((unsigned long long*)&rem_s[w0 + 2 + (c << 6) + lane],
                             (unsigned long long)df[t][c]);
            }
        }

        bar_sync();                               // kept_s / rem_s[w0+2..] final

        // ---- section B (after barrier): broadcast + far-load issue ----
        u64 k0 = kept_s[par][0], k1 = kept_s[par][1];
        int n0 = __popcll(k0);
        int nk = n0 + __popcll(k1);
        u64 below = (1ull << lane) - 1;
        if ((k0 >> lane) & 1) klist[par][__popcll(k0 & below)] = lane;
        if ((k1 >> lane) & 1) klist[par][n0 + __popcll(k1 & below)] = 64 + lane;
        int nkc = (nk < 64) ? nk : 64;
        #pragma unroll
        for (int t = 0; t < 4; ++t) {
            int s = wv + (t << 4);
            bool has = s < nkc;
            int rr = klist[par][has ? s : 0];
            const u64* R = M + (size_t)(w0 * 64 + rr) * NW64;
            #pragma unroll
            for (int c = 0; c < 3; ++c) {
                int w = w0 + 4 + (c << 6) + lane;
                df[t][c] = (has && w < NW64) ? R[w] : 0ull;
            }
        }
        // rare overflow (nk > 64, early pairs): immediate load + commit.
        // Targets >= w0+4 are disjoint from next A's reads (w0+2, w0+3).
        for (int base = 64; base < nk; base += 64) {
            #pragma unroll
            for (int t = 0; t < 4; ++t) {
                int s = base + wv + (t << 4);
                bool has = s < nk;
                int rr = klist[par][has ? s : 0];
                const u64* R = M + (size_t)(w0 * 64 + rr) * NW64;
                #pragma unroll
                for (int c = 0; c < 3; ++c) {
                    int w = w0 + 4 + (c << 6) + lane;
                    u64 v2 = (has && w < NW64) ? R[w] : 0ull;
                    if (v2) atomicOr((unsigned long long*)&rem_s[w], (unsigned long long)v2);
                }
            }
        }
        // no second barrier: next A touches only rem_s (words w0+2/w0+3 were
        // finalized before this barrier) and opposite-parity kept_s/klist.
    }

    for (int t = tid; t < NW64; t += 1024)
        rem_out[(size_t)b * NW64 + t] = rem_s[t];
}

// ---------------------------------------------------------------------------
// Fallback (small ws): original single-block NMS. Writes u32 words into the
// same u64 rem buffer (little-endian layout makes bit positions identical).
// ---------------------------------------------------------------------------
extern __shared__ unsigned char nms_smem[];

__global__ void __launch_bounds__(1024) nms_kernel(const float4* __restrict__ sboxes,
                                                   const uint32_t* __restrict__ ssv,
                                                   const int* __restrict__ nvalid_arr,
                                                   uint32_t* __restrict__ supp_out)
{
#pragma clang fp contract(off)
    int b = blockIdx.x;
    float4*   lbox = (float4*)nms_smem;
    uint32_t* supp = (uint32_t*)(nms_smem + (size_t)LDS_CAP * 16);
    uint32_t* svb  = supp + NW32;

    int nv = nvalid_arr[b];
    const float4* gb = sboxes + (size_t)b * NTOT;
    const uint32_t* gv = ssv + (size_t)b * NTOT;

    for (int t = threadIdx.x; t < NW32; t += 1024) { supp[t] = 0u; svb[t] = 0u; }
    __syncthreads();
    for (int t = threadIdx.x; t < nv; t += 1024) {
        if (t < LDS_CAP) lbox[t] = gb[t];
        if (gv[t]) atomicOr(&svb[t >> 5], 1u << (t & 31));
    }
    __syncthreads();

    for (int i = 0; i < nv; ++i) {
        uint32_t sw = supp[i >> 5];
        if ((sw >> (i & 31)) & 1u) continue;
        uint32_t vw = svb[i >> 5];
        if (!((vw >> (i & 31)) & 1u)) continue;

        float4 bi = (i < LDS_CAP) ? lbox[i] : gb[i];
        float ax1 = bi.x, ay1 = bi.y, ax2 = bi.z, ay2 = bi.w;
        float area_i = (ax2 - ax1) * (ay2 - ay1);

        for (int j = i + 1 + (int)threadIdx.x; j < nv; j += 1024) {
            float4 bj = (j < LDS_CAP) ? lbox[j] : gb[j];
            float xx1 = fmaxf(bj.x, ax1);
            float yy1 = fmaxf(bj.y, ay1);
            float xx2 = fminf(bj.z, ax2);
            float yy2 = fminf(bj.w, ay2);
            float w = fmaxf(xx2 - xx1, 0.0f);
            float h = fmaxf(yy2 - yy1, 0.0f);
            float inter  = w * h;
            float area_j = (bj.z - bj.x) * (bj.w - bj.y);
            float iou = inter / ((area_i + area_j) - inter);
            if (iou > IOU_THR_F) atomicOr(&supp[j >> 5], 1u << (j & 31));
        }
        __syncthreads();
    }

    __syncthreads();
    // u64 layout: u32 word w of image b lives at u32-index b*(2*NW64) + w
    for (int t = threadIdx.x; t < NW32; t += 1024)
        supp_out[(size_t)b * (2 * NW64) + t] = supp[t];
}

// ---------------------------------------------------------------------------
// Kernel D: assemble outputs: dets [B,N,6] then keep [B,N] (as 0/1 floats)
// ---------------------------------------------------------------------------
__global__ void out_kernel(const float4* __restrict__ sboxes, const float* __restrict__ sscore,
                           const int* __restrict__ scls, const uint32_t* __restrict__ ssv,
                           const u64* __restrict__ rem, float* __restrict__ out)
{
    int idx = blockIdx.x * 256 + threadIdx.x;
    if (idx >= NBATCH * NTOT) return;
    int b = idx / NTOT;
    int p = idx - b * NTOT;

    float4 box = sboxes[idx];
    u64 rw = rem[(size_t)b * NW64 + (p >> 6)];
    bool keep = (ssv[idx] != 0u) && !((rw >> (p & 63)) & 1ull);
    float sc = keep ? sscore[idx] : 0.0f;

    float* d = out + (size_t)idx * 6;
    d[0] = box.x; d[1] = box.y; d[2] = box.z; d[3] = box.w;
    d[4] = sc;    d[5] = (float)scls[idx];
    out[(size_t)NBATCH * NTOT * 6 + idx] = keep ? 1.0f : 0.0f;
}

// ---------------------------------------------------------------------------
extern "C" void kernel_launch(void* const* d_in, const int* in_sizes, int n_in,
                              void* d_out, int out_size, void* d_ws, size_t ws_size,
                              hipStream_t stream)
{
    const float* p3b = (const float*)d_in[0];
    const float* p3c = (const float*)d_in[1];
    const float* p3k = (const float*)d_in[2];
    const float* p4b = (const float*)d_in[3];
    const float* p4c = (const float*)d_in[4];
    const float* p4k = (const float*)d_in[5];
    const float* p5b = (const float*)d_in[6];
    const float* p5c = (const float*)d_in[7];
    const float* p5k = (const float*)d_in[8];
    float* out = (float*)d_out;

    // workspace carve-up (256B aligned slabs)
    char* ws = (char*)d_ws;
    size_t off = 0;
    auto alloc = [&](size_t bytes) { size_t o = off; off += (bytes + 255) & ~(size_t)255; return o; };
    const size_t BN = (size_t)NBATCH * NTOT;
    uint64_t* keys      = (uint64_t*)(ws + alloc(BN * 8));
    float4*   boxes_cat = (float4*)  (ws + alloc(BN * 16));
    float*    score     = (float*)   (ws + alloc(BN * 4));
    int*      clsidx    = (int*)     (ws + alloc(BN * 4));
    uint32_t* sv        = (uint32_t*)(ws + alloc(BN * 4));
    float4*   sboxes    = (float4*)  (ws + alloc(BN * 16));
    float*    sscore    = (float*)   (ws + alloc(BN * 4));
    int*      scls      = (int*)     (ws + alloc(BN * 4));
    uint32_t* ssv       = (uint32_t*)(ws + alloc(BN * 4));
    u64*      rem64     = (u64*)     (ws + alloc((size_t)NBATCH * NW64 * 8));
    u64*      validbits = (u64*)     (ws + alloc((size_t)NBATCH * NW64 * 8));
    int*      nvalid    = (int*)     (ws + alloc(NBATCH * 4));
    u64*      diag      = (u64*)     (ws + alloc((size_t)NBATCH * NW64 * 64 * 8));
    u64*      sdiag     = (u64*)     (ws + alloc((size_t)NBATCH * NW64 * 64 * 8));
    u64*      s2diag    = (u64*)     (ws + alloc((size_t)NBATCH * NW64 * 64 * 8));
    u64*      s3diag    = (u64*)     (ws + alloc((size_t)NBATCH * NW64 * 64 * 8));
    u64*      mask      = (u64*)     (ws + alloc((size_t)NBATCH * NTOT * NW64 * 8));
    bool fast = (off <= ws_size);

    hipMemsetAsync(nvalid, 0, NBATCH * 4, stream);
    hipMemsetAsync(validbits, 0, (size_t)NBATCH * NW64 * 8, stream);

    int nblk = (int)((BN + 255) / 256);
    prep_kernel<<<nblk, 256, 0, stream>>>(p3b, p3c, p3k, p4b, p4c, p4k, p5b, p5c, p5k,
                                          keys, boxes_cat, score, clsidx, sv);

    dim3 rgrid((NTOT + 255) / 256, NBATCH);
    rank_kernel<<<rgrid, 256, 0, stream>>>(keys, boxes_cat, score, clsidx, sv,
                                           sboxes, sscore, scls, ssv, validbits, nvalid);

    if (fast) {
        dim3 mgrid((NW64 + 3) / 4, NW64, NBATCH);
        mask_build<<<mgrid, 256, 0, stream>>>(sboxes, mask, diag, sdiag, s2diag, s3diag);
        resolve_kernel<<<NBATCH, 1024, 0, stream>>>(mask, diag, sdiag, s2diag, s3diag,
                                                    validbits, rem64);
    } else {
        hipMemsetAsync(rem64, 0, (size_t)NBATCH * NW64 * 8, stream);
        size_t smem = (size_t)LDS_CAP * 16 + (size_t)NW32 * 4 * 2;
        smem = (smem + 15) & ~(size_t)15;
        hipFuncSetAttribute((const void*)nms_kernel, hipFuncAttributeMaxDynamicSharedMemorySize, (int)smem);
        nms_kernel<<<NBATCH, 1024, smem, stream>>>(sboxes, ssv, nvalid, (uint32_t*)rem64);
    }

    out_kernel<<<nblk, 256, 0, stream>>>(sboxes, sscore, scls, ssv, rem64, out);
}

// Round 10
// 584.879 us; speedup vs baseline: 2.0039x; 1.2065x over previous
//
#include <hip/hip_runtime.h>
#include <stdint.h>

#define NB3 8112
#define NB4 2028
#define NB5 507
#define NTOT 10647           // 8112 + 2028 + 507
#define NBATCH 4
#define NCLS 20
#define NW32 333             // ceil(10647 / 32)
#define NW64 167             // ceil(10647 / 64)
#define NPAIR 84             // ceil(NW64 / 2): 128-box groups for resolve
#define NTAIL 23             // NTOT - 64*(NW64-1)
#define LDS_CAP 9984         // boxes staged in LDS (fallback kernel)
#define CONF_THR_F 0.1f
#define IOU_THR_F 0.45f

typedef unsigned long long u64;

// ---------------------------------------------------------------------------
// Kernel A: per-box score / class argmax / sort key
// ---------------------------------------------------------------------------
__global__ void prep_kernel(const float* __restrict__ p3b, const float* __restrict__ p3c, const float* __restrict__ p3k,
                            const float* __restrict__ p4b, const float* __restrict__ p4c, const float* __restrict__ p4k,
                            const float* __restrict__ p5b, const float* __restrict__ p5c, const float* __restrict__ p5k,
                            uint64_t* __restrict__ keys, float4* __restrict__ boxes_cat,
                            float* __restrict__ score, int* __restrict__ clsidx, uint32_t* __restrict__ svout)
{
#pragma clang fp contract(off)
    int idx = blockIdx.x * 256 + threadIdx.x;
    if (idx >= NBATCH * NTOT) return;
    int b = idx / NTOT;
    int i = idx - b * NTOT;

    const float* bx; const float* cf; const float* cl; int n, off;
    if (i < NB3)            { bx = p3b; cf = p3c; cl = p3k; n = NB3; off = i; }
    else if (i < NB3 + NB4) { bx = p4b; cf = p4c; cl = p4k; n = NB4; off = i - NB3; }
    else                    { bx = p5b; cf = p5c; cl = p5k; n = NB5; off = i - NB3 - NB4; }

    size_t e = (size_t)b * n + off;
    float4 box = *(const float4*)(bx + e * 4);
    float conf = cf[e];
    const float* c = cl + e * NCLS;
    float m = c[0]; int mi = 0;
    #pragma unroll
    for (int k = 1; k < NCLS; ++k) { float v = c[k]; if (v > m) { m = v; mi = k; } }

    bool valid = conf > CONF_THR_F;
    float s = valid ? conf * m : 0.0f;           // exact: single f32 mul, no fma
    uint32_t sb = __float_as_uint(s);            // s >= 0 -> bits monotonic
    keys[idx]      = ((uint64_t)sb << 32) | (uint32_t)(0xFFFFFFFFu - (uint32_t)i);
    boxes_cat[idx] = box;
    score[idx]     = s;
    clsidx[idx]    = mi;
    svout[idx]     = valid ? 1u : 0u;
}

// ---------------------------------------------------------------------------
// Kernel B: stable descending rank sort (rank = #keys strictly greater),
// scatter sorted arrays, build valid bitmap (u64 words) per image
// ---------------------------------------------------------------------------
__global__ void rank_kernel(const uint64_t* __restrict__ keys,
                            const float4* __restrict__ boxes_cat,
                            const float* __restrict__ score,
                            const int* __restrict__ clsidx,
                            const uint32_t* __restrict__ sv,
                            float4* __restrict__ sboxes, float* __restrict__ sscore,
                            int* __restrict__ scls, uint32_t* __restrict__ ssv,
                            u64* __restrict__ validbits, int* __restrict__ nvalid)
{
    int b = blockIdx.y;
    int i = blockIdx.x * 256 + threadIdx.x;
    const uint64_t* kb = keys + (size_t)b * NTOT;
    uint64_t mykey = (i < NTOT) ? kb[i] : 0ull;

    __shared__ uint64_t tile[256];
    int rank = 0;
    for (int t0 = 0; t0 < NTOT; t0 += 256) {
        int j = t0 + threadIdx.x;
        tile[threadIdx.x] = (j < NTOT) ? kb[j] : 0ull;   // 0 never > any real key
        __syncthreads();
        #pragma unroll 8
        for (int t = 0; t < 256; ++t) rank += (tile[t] > mykey) ? 1 : 0;
        __syncthreads();
    }

    if (i < NTOT) {
        size_t src = (size_t)b * NTOT + i;
        size_t dst = (size_t)b * NTOT + rank;
        sboxes[dst] = boxes_cat[src];
        sscore[dst] = score[src];
        scls[dst]   = clsidx[src];
        uint32_t v  = sv[src];
        ssv[dst]    = v;
        if (v) {
            atomicOr(&validbits[(size_t)b * NW64 + (rank >> 6)], 1ull << (rank & 63));
            atomicMax(&nvalid[b], rank + 1);
        }
    }
}

// ---------------------------------------------------------------------------
// Kernel C1 (fast path): build suppression bit-matrix + band buffers.
// mask[(b*NTOT + i)*NW64 + c]: bit k set iff IoU(i, c*64+k)>thr, c*64+k > i,
// c*64+k < NTOT. Only upper-triangle chunks (c >= r) written.
// ldiag [(b*NW64+r)*64+lane] = raw hit row & ((1<<lane)-1): in-word EARLIER
//   suppressors of box r*64+lane (for resolve's wave-parallel fixpoint;
//   validity/removal handled there by intersecting with U|K).
// sdiag/s2diag/s3diag[(b*NW64+r)*64+lane] = mask word at column r+1/r+2/r+3.
// Raw hit word accumulated once; gt/lt/tail masks applied after the loop.
// ---------------------------------------------------------------------------
__global__ void __launch_bounds__(256) mask_build(const float4* __restrict__ sboxes,
                                                  u64* __restrict__ mask,
                                                  u64* __restrict__ ldiag,
                                                  u64* __restrict__ sdiag,
                                                  u64* __restrict__ s2diag,
                                                  u64* __restrict__ s3diag)
{
#pragma clang fp contract(off)
    int c = blockIdx.y;
    if (c < blockIdx.x * 4) return;              // whole block below diagonal
    int b = blockIdx.z;
    int sub = threadIdx.x >> 6;
    int lane = threadIdx.x & 63;
    int r = blockIdx.x * 4 + sub;

    __shared__ float4 cb[64];
    __shared__ float  ca[64];
    if (threadIdx.x < 64) {
        int j = c * 64 + threadIdx.x;
        float4 bj = sboxes[(size_t)b * NTOT + (j < NTOT ? j : NTOT - 1)];
        cb[threadIdx.x] = bj;
        ca[threadIdx.x] = (bj.z - bj.x) * (bj.w - bj.y);
    }
    __syncthreads();

    if (r >= NW64 || c < r) return;              // wave below diagonal / OOB
    int i = r * 64 + lane;
    float4 bi = sboxes[(size_t)b * NTOT + (i < NTOT ? i : NTOT - 1)];
    float ax1 = bi.x, ay1 = bi.y, ax2 = bi.z, ay2 = bi.w;
    float area_i = (ax2 - ax1) * (ay2 - ay1);

    u64 hh = 0;
    #pragma unroll 8
    for (int k = 0; k < 64; ++k) {
        float4 bj = cb[k];
        float xx1 = fmaxf(bj.x, ax1);
        float yy1 = fmaxf(bj.y, ay1);
        float xx2 = fminf(bj.z, ax2);
        float yy2 = fminf(bj.w, ay2);
        float w = fmaxf(xx2 - xx1, 0.0f);
        float h = fmaxf(yy2 - yy1, 0.0f);
        float inter = w * h;
        float iou = inter / ((area_i + ca[k]) - inter);   // matches ref op order
        hh |= (u64)(iou > IOU_THR_F) << k;
    }

    if (i < NTOT) {
        u64 colmask = (c == NW64 - 1) ? ((1ull << NTAIL) - 1) : ~0ull;
        u64 mw = hh & colmask;
        size_t bl = ((size_t)b * NW64 + r) * 64 + lane;
        if (c == r) {
            u64 gtmask = (lane < 63) ? (~0ull << (lane + 1)) : 0ull;
            mask[((size_t)b * NTOT + i) * NW64 + c] = mw & gtmask;
            ldiag[bl] = hh & ((1ull << lane) - 1);
        } else {
            mask[((size_t)b * NTOT + i) * NW64 + c] = mw;
            if (c == r + 1) sdiag [bl] = mw;
            if (c == r + 2) s2diag[bl] = mw;
            if (c == r + 3) s3diag[bl] = mw;
        }
    }
}

// ---------------------------------------------------------------------------
// Kernel C2 (fast path): greedy resolve. R9's proven pair schedule (single
// barrier, parity buffers, near-word band atomics, deferred far-OR), but the
// serial readlane chain (the fitted ~200+ us term) is replaced by an in-word
// WAVE-PARALLEL FIXPOINT on wave 0:
//   U = alive; K = 0
//   round: nk = ballot(l in U && (ldiag_l & (U|K)) == 0)   // kept
//          nr = ballot(l in U && (ldiag_l & K)   != 0)     // removed
//          K |= nk; U &= ~(nk|nr)
// Exactly greedy (kept <=> no earlier kept suppressor); the minimal U bit is
// decided every round -> terminates in chain-depth rounds (random boxes: ~2-5).
// Round cost ~40cy, no readlane/SALU hazards, no branch per box.
// Word0 -> word1 suppression S1: same-address LDS atomicOr of sdiag over K0's
// kept lanes + one read-back, once per pair.
// ---------------------------------------------------------------------------
static __device__ __forceinline__ void bar_sync()
{
    asm volatile("s_waitcnt lgkmcnt(0)" ::: "memory");
    __builtin_amdgcn_s_barrier();
    asm volatile("" ::: "memory");
}

static __device__ __forceinline__ u64 rfl64(u64 x)
{
    uint32_t lo = __builtin_amdgcn_readfirstlane((uint32_t)x);
    uint32_t hi = __builtin_amdgcn_readfirstlane((uint32_t)(x >> 32));
    return ((u64)hi << 32) | (u64)lo;
}

__global__ void __launch_bounds__(1024) resolve_kernel(const u64* __restrict__ mask,
                                                       const u64* __restrict__ ldiag,
                                                       const u64* __restrict__ sdiag,
                                                       const u64* __restrict__ s2diag,
                                                       const u64* __restrict__ s3diag,
                                                       const u64* __restrict__ validbits,
                                                       u64* __restrict__ rem_out)
{
    int b = blockIdx.x;
    int tid = threadIdx.x;
    int lane = tid & 63;
    int wv = tid >> 6;
    const u64* M  = mask   + (size_t)b * NTOT * NW64;
    const u64* LD = ldiag  + (size_t)b * NW64 * 64;
    const u64* SD = sdiag  + (size_t)b * NW64 * 64;
    const u64* S2 = s2diag + (size_t)b * NW64 * 64;
    const u64* S3 = s3diag + (size_t)b * NW64 * 64;
    const u64* V  = validbits + (size_t)b * NW64;

    __shared__ u64 rem_s[NW64 + 1];              // +1: word index 167 (pair tail)
    __shared__ u64 v_s[NW64 + 1];                // v_s[167] = 0 -> alive1 = 0
    __shared__ u64 kept_s[2][2];                 // parity double-buffered
    __shared__ int klist[2][128];
    __shared__ u64 sc_s;                         // wave-0 S1 reduction scratch

    for (int t = tid; t < NW64; t += 1024) { rem_s[t] = 0ull; v_s[t] = V[t]; }
    if (tid == 0) {
        rem_s[NW64] = 0ull; v_s[NW64] = 0ull;
        kept_s[0][0] = kept_s[0][1] = kept_s[1][0] = kept_s[1][1] = 0ull;
        klist[0][0] = 0; klist[1][0] = 0; sc_s = 0ull;
    }

    // wave 0's register bands for pair 0 (word0 = 0, word1 = 1)
    u64 ld0 = 0, sd0 = 0, s2_0 = 0, s3_0 = 0, ld1 = 0, s1_1 = 0, s2_1 = 0;
    if (wv == 0) {
        ld0 = LD[lane];      sd0 = SD[lane];
        s2_0 = S2[lane];     s3_0 = S3[lane];
        ld1 = LD[64 + lane]; s1_1 = SD[64 + lane]; s2_1 = S2[64 + lane];
    }

    u64 df[4][3];                                // deferred far-OR payload
    #pragma unroll
    for (int t = 0; t < 4; ++t) {
        #pragma unroll
        for (int c = 0; c < 3; ++c) df[t][c] = 0ull;
    }

    bar_sync();

    for (int p = 0; p < NPAIR; ++p) {
        int par = p & 1;
        int w0 = 2 * p, w1 = 2 * p + 1;

        // ---- section A (before barrier) ----
        if (wv == 0) {
            u64 a0pre = rfl64(v_s[w0] & ~rem_s[w0]);
            u64 a1pre = rfl64(v_s[w1] & ~rem_s[w1]);   // w1==167 -> pad gives 0

            // word0 fixpoint
            u64 U = a0pre, K0 = 0;
            while (U) {
                u64 UK = U | K0;
                bool inU = (U >> lane) & 1;
                u64 nk = __ballot(inU && ((ld0 & UK) == 0ull));
                u64 nr = __ballot(inU && ((ld0 & K0) != 0ull));
                K0 |= nk;
                U &= ~(nk | nr);
            }

            // S1 = OR of sdiag over word0's kept lanes (same-address LDS atomic)
            if (lane == 0) sc_s = 0ull;
            if (((K0 >> lane) & 1) && sd0)
                atomicOr((unsigned long long*)&sc_s, (unsigned long long)sd0);
            asm volatile("s_waitcnt lgkmcnt(0)" ::: "memory");
            u64 S1 = sc_s;

            // word1 fixpoint (word0's suppressions pre-applied -> exactly greedy)
            u64 U1 = a1pre & ~S1, K1 = 0;
            while (U1) {
                u64 UK = U1 | K1;
                bool inU = (U1 >> lane) & 1;
                u64 nk = __ballot(inU && ((ld1 & UK) == 0ull));
                u64 nr = __ballot(inU && ((ld1 & K1) != 0ull));
                K1 |= nk;
                U1 &= ~(nk | nr);
            }

            if (lane == 0) {
                kept_s[par][0] = K0; kept_s[par][1] = K1;
                u64 sup0 = a0pre & ~K0;            // in-word + none (K0 ⊆ a0pre)
                u64 sup1 = a1pre & ~K1;            // includes S1 victims
                if (sup0) atomicOr((unsigned long long*)&rem_s[w0], (unsigned long long)sup0);
                if (sup1) atomicOr((unsigned long long*)&rem_s[w1], (unsigned long long)sup1);
            }
            // near words w0+2 / w0+3 from register bands (guard by TARGET index;
            // band values are garbage when the source column chunk >= NW64)
            int w2 = w0 + 2, w3 = w0 + 3;
            bool h2 = w2 < NW64, h3 = w3 < NW64;
            if ((K0 >> lane) & 1) {
                if (h2 && s2_0) atomicOr((unsigned long long*)&rem_s[w2], (unsigned long long)s2_0);
                if (h3 && s3_0) atomicOr((unsigned long long*)&rem_s[w3], (unsigned long long)s3_0);
            }
            if ((K1 >> lane) & 1) {
                if (h2 && s1_1) atomicOr((unsigned long long*)&rem_s[w2], (unsigned long long)s1_1);
                if (h3 && s2_1) atomicOr((unsigned long long*)&rem_s[w3], (unsigned long long)s2_1);
            }
            // prefetch next pair's bands (consumed after next barrier)
            int pn = (p + 1 < NPAIR) ? p + 1 : p;
            int i0 = 2 * pn;
            int i1 = (2 * pn + 1 < NW64) ? 2 * pn + 1 : NW64 - 1;
            ld0  = LD[(size_t)i0 * 64 + lane];
            sd0  = SD[(size_t)i0 * 64 + lane];
            s2_0 = S2[(size_t)i0 * 64 + lane];
            s3_0 = S3[(size_t)i0 * 64 + lane];
            ld1  = LD[(size_t)i1 * 64 + lane];
            s1_1 = SD[(size_t)i1 * 64 + lane];
            s2_1 = S2[(size_t)i1 * 64 + lane];
        }
        // all waves: commit deferred far-ORs from pair p-1 (targets >= w0+2;
        // df zero-predicated at issue bounds the index). For waves 1-15 the
        // vmcnt stall here overlaps wave 0's fixpoints.
        #pragma unroll
        for (int t = 0; t < 4; ++t) {
            #pragma unroll
            for (int c = 0; c < 3; ++c) {
                if (df[t][c])
                    atomicOr((unsigned long long*)&rem_s[w0 + 2 + (c << 6) + lane],
                             (unsigned long long)df[t][c]);
            }
        }

        bar_sync();                               // kept_s / rem_s[w0+2..] final

        // ---- section B (after barrier): broadcast + far-load issue ----
        u64 k0 = kept_s[par][0], k1 = kept_s[par][1];
        int n0 = __popcll(k0);
        int nk = n0 + __popcll(k1);
        u64 below = (1ull << lane) - 1;
        if ((k0 >> lane) & 1) klist[par][__popcll(k0 & below)] = lane;
        if ((k1 >> lane) & 1) klist[par][n0 + __popcll(k1 & below)] = 64 + lane;
        int nkc = (nk < 64) ? nk : 64;
        #pragma unroll
        for (int t = 0; t < 4; ++t) {
            int s = wv + (t << 4);
            bool has = s < nkc;
            int rr = klist[par][has ? s : 0];
            const u64* R = M + (size_t)(w0 * 64 + rr) * NW64;
            #pragma unroll
            for (int c = 0; c < 3; ++c) {
                int w = w0 + 4 + (c << 6) + lane;
                df[t][c] = (has && w < NW64) ? R[w] : 0ull;
            }
        }
        // rare overflow (nk > 64, early pairs): immediate load + commit.
        // Targets >= w0+4 are disjoint from next A's reads (w0+2, w0+3).
        for (int base = 64; base < nk; base += 64) {
            #pragma unroll
            for (int t = 0; t < 4; ++t) {
                int s = base + wv + (t << 4);
                bool has = s < nk;
                int rr = klist[par][has ? s : 0];
                const u64* R = M + (size_t)(w0 * 64 + rr) * NW64;
                #pragma unroll
                for (int c = 0; c < 3; ++c) {
                    int w = w0 + 4 + (c << 6) + lane;
                    u64 v2 = (has && w < NW64) ? R[w] : 0ull;
                    if (v2) atomicOr((unsigned long long*)&rem_s[w], (unsigned long long)v2);
                }
            }
        }
        // no second barrier: next A touches only rem_s (words w0+2/w0+3 were
        // finalized before this barrier) and opposite-parity kept_s/klist.
    }

    for (int t = tid; t < NW64; t += 1024)
        rem_out[(size_t)b * NW64 + t] = rem_s[t];
}

// ---------------------------------------------------------------------------
// Fallback (small ws): original single-block NMS. Writes u32 words into the
// same u64 rem buffer (little-endian layout makes bit positions identical).
// ---------------------------------------------------------------------------
extern __shared__ unsigned char nms_smem[];

__global__ void __launch_bounds__(1024) nms_kernel(const float4* __restrict__ sboxes,
                                                   const uint32_t* __restrict__ ssv,
                                                   const int* __restrict__ nvalid_arr,
                                                   uint32_t* __restrict__ supp_out)
{
#pragma clang fp contract(off)
    int b = blockIdx.x;
    float4*   lbox = (float4*)nms_smem;
    uint32_t* supp = (uint32_t*)(nms_smem + (size_t)LDS_CAP * 16);
    uint32_t* svb  = supp + NW32;

    int nv = nvalid_arr[b];
    const float4* gb = sboxes + (size_t)b * NTOT;
    const uint32_t* gv = ssv + (size_t)b * NTOT;

    for (int t = threadIdx.x; t < NW32; t += 1024) { supp[t] = 0u; svb[t] = 0u; }
    __syncthreads();
    for (int t = threadIdx.x; t < nv; t += 1024) {
        if (t < LDS_CAP) lbox[t] = gb[t];
        if (gv[t]) atomicOr(&svb[t >> 5], 1u << (t & 31));
    }
    __syncthreads();

    for (int i = 0; i < nv; ++i) {
        uint32_t sw = supp[i >> 5];
        if ((sw >> (i & 31)) & 1u) continue;
        uint32_t vw = svb[i >> 5];
        if (!((vw >> (i & 31)) & 1u)) continue;

        float4 bi = (i < LDS_CAP) ? lbox[i] : gb[i];
        float ax1 = bi.x, ay1 = bi.y, ax2 = bi.z, ay2 = bi.w;
        float area_i = (ax2 - ax1) * (ay2 - ay1);

        for (int j = i + 1 + (int)threadIdx.x; j < nv; j += 1024) {
            float4 bj = (j < LDS_CAP) ? lbox[j] : gb[j];
            float xx1 = fmaxf(bj.x, ax1);
            float yy1 = fmaxf(bj.y, ay1);
            float xx2 = fminf(bj.z, ax2);
            float yy2 = fminf(bj.w, ay2);
            float w = fmaxf(xx2 - xx1, 0.0f);
            float h = fmaxf(yy2 - yy1, 0.0f);
            float inter  = w * h;
            float area_j = (bj.z - bj.x) * (bj.w - bj.y);
            float iou = inter / ((area_i + area_j) - inter);
            if (iou > IOU_THR_F) atomicOr(&supp[j >> 5], 1u << (j & 31));
        }
        __syncthreads();
    }

    __syncthreads();
    // u64 layout: u32 word w of image b lives at u32-index b*(2*NW64) + w
    for (int t = threadIdx.x; t < NW32; t += 1024)
        supp_out[(size_t)b * (2 * NW64) + t] = supp[t];
}

// ---------------------------------------------------------------------------
// Kernel D: assemble outputs: dets [B,N,6] then keep [B,N] (as 0/1 floats)
// ---------------------------------------------------------------------------
__global__ void out_kernel(const float4* __restrict__ sboxes, const float* __restrict__ sscore,
                           const int* __restrict__ scls, const uint32_t* __restrict__ ssv,
                           const u64* __restrict__ rem, float* __restrict__ out)
{
    int idx = blockIdx.x * 256 + threadIdx.x;
    if (idx >= NBATCH * NTOT) return;
    int b = idx / NTOT;
    int p = idx - b * NTOT;

    float4 box = sboxes[idx];
    u64 rw = rem[(size_t)b * NW64 + (p >> 6)];
    bool keep = (ssv[idx] != 0u) && !((rw >> (p & 63)) & 1ull);
    float sc = keep ? sscore[idx] : 0.0f;

    float* d = out + (size_t)idx * 6;
    d[0] = box.x; d[1] = box.y; d[2] = box.z; d[3] = box.w;
    d[4] = sc;    d[5] = (float)scls[idx];
    out[(size_t)NBATCH * NTOT * 6 + idx] = keep ? 1.0f : 0.0f;
}

// ---------------------------------------------------------------------------
extern "C" void kernel_launch(void* const* d_in, const int* in_sizes, int n_in,
                              void* d_out, int out_size, void* d_ws, size_t ws_size,
                              hipStream_t stream)
{
    const float* p3b = (const float*)d_in[0];
    const float* p3c = (const float*)d_in[1];
    const float* p3k = (const float*)d_in[2];
    const float* p4b = (const float*)d_in[3];
    const float* p4c = (const float*)d_in[4];
    const float* p4k = (const float*)d_in[5];
    const float* p5b = (const float*)d_in[6];
    const float* p5c = (const float*)d_in[7];
    const float* p5k = (const float*)d_in[8];
    float* out = (float*)d_out;

    // workspace carve-up (256B aligned slabs)
    char* ws = (char*)d_ws;
    size_t off = 0;
    auto alloc = [&](size_t bytes) { size_t o = off; off += (bytes + 255) & ~(size_t)255; return o; };
    const size_t BN = (size_t)NBATCH * NTOT;
    uint64_t* keys      = (uint64_t*)(ws + alloc(BN * 8));
    float4*   boxes_cat = (float4*)  (ws + alloc(BN * 16));
    float*    score     = (float*)   (ws + alloc(BN * 4));
    int*      clsidx    = (int*)     (ws + alloc(BN * 4));
    uint32_t* sv        = (uint32_t*)(ws + alloc(BN * 4));
    float4*   sboxes    = (float4*)  (ws + alloc(BN * 16));
    float*    sscore    = (float*)   (ws + alloc(BN * 4));
    int*      scls      = (int*)     (ws + alloc(BN * 4));
    uint32_t* ssv       = (uint32_t*)(ws + alloc(BN * 4));
    u64*      rem64     = (u64*)     (ws + alloc((size_t)NBATCH * NW64 * 8));
    u64*      validbits = (u64*)     (ws + alloc((size_t)NBATCH * NW64 * 8));
    int*      nvalid    = (int*)     (ws + alloc(NBATCH * 4));
    u64*      ldiag     = (u64*)     (ws + alloc((size_t)NBATCH * NW64 * 64 * 8));
    u64*      sdiag     = (u64*)     (ws + alloc((size_t)NBATCH * NW64 * 64 * 8));
    u64*      s2diag    = (u64*)     (ws + alloc((size_t)NBATCH * NW64 * 64 * 8));
    u64*      s3diag    = (u64*)     (ws + alloc((size_t)NBATCH * NW64 * 64 * 8));
    u64*      mask      = (u64*)     (ws + alloc((size_t)NBATCH * NTOT * NW64 * 8));
    bool fast = (off <= ws_size);

    hipMemsetAsync(nvalid, 0, NBATCH * 4, stream);
    hipMemsetAsync(validbits, 0, (size_t)NBATCH * NW64 * 8, stream);

    int nblk = (int)((BN + 255) / 256);
    prep_kernel<<<nblk, 256, 0, stream>>>(p3b, p3c, p3k, p4b, p4c, p4k, p5b, p5c, p5k,
                                          keys, boxes_cat, score, clsidx, sv);

    dim3 rgrid((NTOT + 255) / 256, NBATCH);
    rank_kernel<<<rgrid, 256, 0, stream>>>(keys, boxes_cat, score, clsidx, sv,
                                           sboxes, sscore, scls, ssv, validbits, nvalid);

    if (fast) {
        dim3 mgrid((NW64 + 3) / 4, NW64, NBATCH);
        mask_build<<<mgrid, 256, 0, stream>>>(sboxes, mask, ldiag, sdiag, s2diag, s3diag);
        resolve_kernel<<<NBATCH, 1024, 0, stream>>>(mask, ldiag, sdiag, s2diag, s3diag,
                                                    validbits, rem64);
    } else {
        hipMemsetAsync(rem64, 0, (size_t)NBATCH * NW64 * 8, stream);
        size_t smem = (size_t)LDS_CAP * 16 + (size_t)NW32 * 4 * 2;
        smem = (smem + 15) & ~(size_t)15;
        hipFuncSetAttribute((const void*)nms_kernel, hipFuncAttributeMaxDynamicSharedMemorySize, (int)smem);
        nms_kernel<<<NBATCH, 1024, smem, stream>>>(sboxes, ssv, nvalid, (uint32_t*)rem64);
    }

    out_kernel<<<nblk, 256, 0, stream>>>(sboxes, sscore, scls, ssv, rem64, out);
}

// Round 11
// 549.506 us; speedup vs baseline: 2.1329x; 1.0644x over previous
//
#include <hip/hip_runtime.h>
#include <stdint.h>

#define NB3 8112
#define NB4 2028
#define NB5 507
#define NTOT 10647           // 8112 + 2028 + 507
#define NBATCH 4
#define NCLS 20
#define NW32 333             // ceil(10647 / 32)
#define NW64 167             // ceil(10647 / 64)
#define NPAIR 84             // ceil(NW64 / 2): 128-box groups for resolve
#define NTAIL 23             // NTOT - 64*(NW64-1)
#define LDS_CAP 9984         // boxes staged in LDS (fallback kernel)
#define CONF_THR_F 0.1f
#define IOU_THR_F 0.45f
// Upper midpoint of 0.45f: RN(x) > 0.45f  <=>  x > IOU_MID (0.45f mantissa LSB
// is even -> tie at the midpoint rounds DOWN). 25-bit m x 24-bit union is
// exact in f64, so (double)inter > IOU_MID*(double)union is bit-equivalent to
// the reference's f32-divide-then-compare.
#define IOU_MID ((double)IOU_THR_F + 0x1p-26)

typedef unsigned long long u64;

// ---------------------------------------------------------------------------
// Kernel A: per-box score / class argmax / sort key.
// Also zeroes validbits/nvalid (folds the two hipMemsetAsync dispatches).
// ---------------------------------------------------------------------------
__global__ void prep_kernel(const float* __restrict__ p3b, const float* __restrict__ p3c, const float* __restrict__ p3k,
                            const float* __restrict__ p4b, const float* __restrict__ p4c, const float* __restrict__ p4k,
                            const float* __restrict__ p5b, const float* __restrict__ p5c, const float* __restrict__ p5k,
                            uint64_t* __restrict__ keys, float4* __restrict__ boxes_cat,
                            float* __restrict__ score, int* __restrict__ clsidx, uint32_t* __restrict__ svout,
                            u64* __restrict__ validbits, int* __restrict__ nvalid)
{
#pragma clang fp contract(off)
    int idx = blockIdx.x * 256 + threadIdx.x;
    if (idx < NBATCH * NW64) validbits[idx] = 0ull;
    if (idx < NBATCH) nvalid[idx] = 0;
    if (idx >= NBATCH * NTOT) return;
    int b = idx / NTOT;
    int i = idx - b * NTOT;

    const float* bx; const float* cf; const float* cl; int n, off;
    if (i < NB3)            { bx = p3b; cf = p3c; cl = p3k; n = NB3; off = i; }
    else if (i < NB3 + NB4) { bx = p4b; cf = p4c; cl = p4k; n = NB4; off = i - NB3; }
    else                    { bx = p5b; cf = p5c; cl = p5k; n = NB5; off = i - NB3 - NB4; }

    size_t e = (size_t)b * n + off;
    float4 box = *(const float4*)(bx + e * 4);
    float conf = cf[e];
    const float* c = cl + e * NCLS;
    float m = c[0]; int mi = 0;
    #pragma unroll
    for (int k = 1; k < NCLS; ++k) { float v = c[k]; if (v > m) { m = v; mi = k; } }

    bool valid = conf > CONF_THR_F;
    float s = valid ? conf * m : 0.0f;           // exact: single f32 mul, no fma
    uint32_t sb = __float_as_uint(s);            // s >= 0 -> bits monotonic
    keys[idx]      = ((uint64_t)sb << 32) | (uint32_t)(0xFFFFFFFFu - (uint32_t)i);
    boxes_cat[idx] = box;
    score[idx]     = s;
    clsidx[idx]    = mi;
    svout[idx]     = valid ? 1u : 0u;
}

// ---------------------------------------------------------------------------
// Kernel B: stable descending rank sort (rank = #keys strictly greater),
// scatter sorted arrays, build valid bitmap (u64 words) per image
// ---------------------------------------------------------------------------
__global__ void rank_kernel(const uint64_t* __restrict__ keys,
                            const float4* __restrict__ boxes_cat,
                            const float* __restrict__ score,
                            const int* __restrict__ clsidx,
                            const uint32_t* __restrict__ sv,
                            float4* __restrict__ sboxes, float* __restrict__ sscore,
                            int* __restrict__ scls, uint32_t* __restrict__ ssv,
                            u64* __restrict__ validbits, int* __restrict__ nvalid)
{
    int b = blockIdx.y;
    int i = blockIdx.x * 256 + threadIdx.x;
    const uint64_t* kb = keys + (size_t)b * NTOT;
    uint64_t mykey = (i < NTOT) ? kb[i] : 0ull;

    __shared__ uint64_t tile[256];
    int rank = 0;
    for (int t0 = 0; t0 < NTOT; t0 += 256) {
        int j = t0 + threadIdx.x;
        tile[threadIdx.x] = (j < NTOT) ? kb[j] : 0ull;   // 0 never > any real key
        __syncthreads();
        #pragma unroll 8
        for (int t = 0; t < 256; ++t) rank += (tile[t] > mykey) ? 1 : 0;
        __syncthreads();
    }

    if (i < NTOT) {
        size_t src = (size_t)b * NTOT + i;
        size_t dst = (size_t)b * NTOT + rank;
        sboxes[dst] = boxes_cat[src];
        sscore[dst] = score[src];
        scls[dst]   = clsidx[src];
        uint32_t v  = sv[src];
        ssv[dst]    = v;
        if (v) {
            atomicOr(&validbits[(size_t)b * NW64 + (rank >> 6)], 1ull << (rank & 63));
            atomicMax(&nvalid[b], rank + 1);
        }
    }
}

// ---------------------------------------------------------------------------
// Kernel C1 (fast path): build suppression bit-matrix + band buffers.
// The IoU predicate uses the exact f64 midpoint comparison (see IOU_MID) --
// bit-identical to f32 divide-then-compare, ~25-35% fewer instructions.
// mask[(b*NTOT + i)*NW64 + c]: bit k set iff hit && c*64+k > i && c*64+k < NTOT.
// ldiag [(b*NW64+r)*64+lane] = raw hit row & ((1<<lane)-1): in-word EARLIER
//   suppressors (resolve's fixpoint masks validity/removal via U|K).
// sdiag/s2diag/s3diag[(b*NW64+r)*64+lane] = mask word at column r+1/r+2/r+3.
// ---------------------------------------------------------------------------
__global__ void __launch_bounds__(256) mask_build(const float4* __restrict__ sboxes,
                                                  u64* __restrict__ mask,
                                                  u64* __restrict__ ldiag,
                                                  u64* __restrict__ sdiag,
                                                  u64* __restrict__ s2diag,
                                                  u64* __restrict__ s3diag)
{
#pragma clang fp contract(off)
    int c = blockIdx.y;
    if (c < blockIdx.x * 4) return;              // whole block below diagonal
    int b = blockIdx.z;
    int sub = threadIdx.x >> 6;
    int lane = threadIdx.x & 63;
    int r = blockIdx.x * 4 + sub;

    __shared__ float4 cb[64];
    __shared__ float  ca[64];
    if (threadIdx.x < 64) {
        int j = c * 64 + threadIdx.x;
        float4 bj = sboxes[(size_t)b * NTOT + (j < NTOT ? j : NTOT - 1)];
        cb[threadIdx.x] = bj;
        ca[threadIdx.x] = (bj.z - bj.x) * (bj.w - bj.y);
    }
    __syncthreads();

    if (r >= NW64 || c < r) return;              // wave below diagonal / OOB
    int i = r * 64 + lane;
    float4 bi = sboxes[(size_t)b * NTOT + (i < NTOT ? i : NTOT - 1)];
    float ax1 = bi.x, ay1 = bi.y, ax2 = bi.z, ay2 = bi.w;
    float area_i = (ax2 - ax1) * (ay2 - ay1);

    u64 hh = 0;
    #pragma unroll 8
    for (int k = 0; k < 64; ++k) {
        float4 bj = cb[k];
        float xx1 = fmaxf(bj.x, ax1);
        float yy1 = fmaxf(bj.y, ay1);
        float xx2 = fminf(bj.z, ax2);
        float yy2 = fminf(bj.w, ay2);
        float w = fmaxf(xx2 - xx1, 0.0f);
        float h = fmaxf(yy2 - yy1, 0.0f);
        float inter = w * h;
        float uni = (area_i + ca[k]) - inter;    // same f32 ops as reference
        bool hit = (double)inter > IOU_MID * (double)uni;   // == RN(inter/uni) > 0.45f
        hh |= (u64)hit << k;
    }

    if (i < NTOT) {
        u64 colmask = (c == NW64 - 1) ? ((1ull << NTAIL) - 1) : ~0ull;
        u64 mw = hh & colmask;
        size_t bl = ((size_t)b * NW64 + r) * 64 + lane;
        if (c == r) {
            u64 gtmask = (lane < 63) ? (~0ull << (lane + 1)) : 0ull;
            mask[((size_t)b * NTOT + i) * NW64 + c] = mw & gtmask;
            ldiag[bl] = hh & ((1ull << lane) - 1);
        } else {
            mask[((size_t)b * NTOT + i) * NW64 + c] = mw;
            if (c == r + 1) sdiag [bl] = mw;
            if (c == r + 2) s2diag[bl] = mw;
            if (c == r + 3) s3diag[bl] = mw;
        }
    }
}

// ---------------------------------------------------------------------------
// Kernel C2 (fast path): greedy resolve -- R10's proven structure (pair
// schedule, wave-parallel in-word ballot fixpoint on wave 0, single barrier,
// parity buffers, near-word band atomics, deferred far-OR) + fused output
// tail (folds out_kernel: block b writes image b's dets/keep from LDS rem_s).
// ---------------------------------------------------------------------------
static __device__ __forceinline__ void bar_sync()
{
    asm volatile("s_waitcnt lgkmcnt(0)" ::: "memory");
    __builtin_amdgcn_s_barrier();
    asm volatile("" ::: "memory");
}

static __device__ __forceinline__ u64 rfl64(u64 x)
{
    uint32_t lo = __builtin_amdgcn_readfirstlane((uint32_t)x);
    uint32_t hi = __builtin_amdgcn_readfirstlane((uint32_t)(x >> 32));
    return ((u64)hi << 32) | (u64)lo;
}

__global__ void __launch_bounds__(1024) resolve_kernel(const u64* __restrict__ mask,
                                                       const u64* __restrict__ ldiag,
                                                       const u64* __restrict__ sdiag,
                                                       const u64* __restrict__ s2diag,
                                                       const u64* __restrict__ s3diag,
                                                       const u64* __restrict__ validbits,
                                                       const float4* __restrict__ sboxes,
                                                       const float* __restrict__ sscore,
                                                       const int* __restrict__ scls,
                                                       const uint32_t* __restrict__ ssv,
                                                       u64* __restrict__ rem_out,
                                                       float* __restrict__ out)
{
    int b = blockIdx.x;
    int tid = threadIdx.x;
    int lane = tid & 63;
    int wv = tid >> 6;
    const u64* M  = mask   + (size_t)b * NTOT * NW64;
    const u64* LD = ldiag  + (size_t)b * NW64 * 64;
    const u64* SD = sdiag  + (size_t)b * NW64 * 64;
    const u64* S2 = s2diag + (size_t)b * NW64 * 64;
    const u64* S3 = s3diag + (size_t)b * NW64 * 64;
    const u64* V  = validbits + (size_t)b * NW64;

    __shared__ u64 rem_s[NW64 + 1];              // +1: word index 167 (pair tail)
    __shared__ u64 v_s[NW64 + 1];                // v_s[167] = 0 -> alive1 = 0
    __shared__ u64 kept_s[2][2];                 // parity double-buffered
    __shared__ int klist[2][128];
    __shared__ u64 sc_s;                         // wave-0 S1 reduction scratch

    for (int t = tid; t < NW64; t += 1024) { rem_s[t] = 0ull; v_s[t] = V[t]; }
    if (tid == 0) {
        rem_s[NW64] = 0ull; v_s[NW64] = 0ull;
        kept_s[0][0] = kept_s[0][1] = kept_s[1][0] = kept_s[1][1] = 0ull;
        klist[0][0] = 0; klist[1][0] = 0; sc_s = 0ull;
    }

    // wave 0's register bands for pair 0 (word0 = 0, word1 = 1)
    u64 ld0 = 0, sd0 = 0, s2_0 = 0, s3_0 = 0, ld1 = 0, s1_1 = 0, s2_1 = 0;
    if (wv == 0) {
        ld0 = LD[lane];      sd0 = SD[lane];
        s2_0 = S2[lane];     s3_0 = S3[lane];
        ld1 = LD[64 + lane]; s1_1 = SD[64 + lane]; s2_1 = S2[64 + lane];
    }

    u64 df[4][3];                                // deferred far-OR payload
    #pragma unroll
    for (int t = 0; t < 4; ++t) {
        #pragma unroll
        for (int c = 0; c < 3; ++c) df[t][c] = 0ull;
    }

    bar_sync();

    for (int p = 0; p < NPAIR; ++p) {
        int par = p & 1;
        int w0 = 2 * p, w1 = 2 * p + 1;

        // ---- section A (before barrier) ----
        if (wv == 0) {
            u64 a0pre = rfl64(v_s[w0] & ~rem_s[w0]);
            u64 a1pre = rfl64(v_s[w1] & ~rem_s[w1]);   // w1==167 -> pad gives 0

            // word0 fixpoint
            u64 U = a0pre, K0 = 0;
            while (U) {
                u64 UK = U | K0;
                bool inU = (U >> lane) & 1;
                u64 nk = __ballot(inU && ((ld0 & UK) == 0ull));
                u64 nr = __ballot(inU && ((ld0 & K0) != 0ull));
                K0 |= nk;
                U &= ~(nk | nr);
            }

            // S1 = OR of sdiag over word0's kept lanes (same-address LDS atomic)
            if (lane == 0) sc_s = 0ull;
            if (((K0 >> lane) & 1) && sd0)
                atomicOr((unsigned long long*)&sc_s, (unsigned long long)sd0);
            asm volatile("s_waitcnt lgkmcnt(0)" ::: "memory");
            u64 S1 = sc_s;

            // word1 fixpoint (word0's suppressions pre-applied -> exactly greedy)
            u64 U1 = a1pre & ~S1, K1 = 0;
            while (U1) {
                u64 UK = U1 | K1;
                bool inU = (U1 >> lane) & 1;
                u64 nk = __ballot(inU && ((ld1 & UK) == 0ull));
                u64 nr = __ballot(inU && ((ld1 & K1) != 0ull));
                K1 |= nk;
                U1 &= ~(nk | nr);
            }

            if (lane == 0) {
                kept_s[par][0] = K0; kept_s[par][1] = K1;
                u64 sup0 = a0pre & ~K0;            // in-word (K0 subset of a0pre)
                u64 sup1 = a1pre & ~K1;            // includes S1 victims
                if (sup0) atomicOr((unsigned long long*)&rem_s[w0], (unsigned long long)sup0);
                if (sup1) atomicOr((unsigned long long*)&rem_s[w1], (unsigned long long)sup1);
            }
            // near words w0+2 / w0+3 from register bands (guard by TARGET index;
            // band values are garbage when the source column chunk >= NW64)
            int w2 = w0 + 2, w3 = w0 + 3;
            bool h2 = w2 < NW64, h3 = w3 < NW64;
            if ((K0 >> lane) & 1) {
                if (h2 && s2_0) atomicOr((unsigned long long*)&rem_s[w2], (unsigned long long)s2_0);
                if (h3 && s3_0) atomicOr((unsigned long long*)&rem_s[w3], (unsigned long long)s3_0);
            }
            if ((K1 >> lane) & 1) {
                if (h2 && s1_1) atomicOr((unsigned long long*)&rem_s[w2], (unsigned long long)s1_1);
                if (h3 && s2_1) atomicOr((unsigned long long*)&rem_s[w3], (unsigned long long)s2_1);
            }
            // prefetch next pair's bands (consumed after next barrier)
            int pn = (p + 1 < NPAIR) ? p + 1 : p;
            int i0 = 2 * pn;
            int i1 = (2 * pn + 1 < NW64) ? 2 * pn + 1 : NW64 - 1;
            ld0  = LD[(size_t)i0 * 64 + lane];
            sd0  = SD[(size_t)i0 * 64 + lane];
            s2_0 = S2[(size_t)i0 * 64 + lane];
            s3_0 = S3[(size_t)i0 * 64 + lane];
            ld1  = LD[(size_t)i1 * 64 + lane];
            s1_1 = SD[(size_t)i1 * 64 + lane];
            s2_1 = S2[(size_t)i1 * 64 + lane];
        }
        // all waves: commit deferred far-ORs from pair p-1 (targets >= w0+2;
        // df zero-predicated at issue bounds the index). For waves 1-15 the
        // vmcnt stall here overlaps wave 0's fixpoints.
        #pragma unroll
        for (int t = 0; t < 4; ++t) {
            #pragma unroll
            for (int c = 0; c < 3; ++c) {
                if (df[t][c])
                    atomicOr((unsigned long long*)&rem_s[w0 + 2 + (c << 6) + lane],
                             (unsigned long long)df[t][c]);
            }
        }

        bar_sync();                               // kept_s / rem_s[w0+2..] final

        // ---- section B (after barrier): broadcast + far-load issue ----
        u64 k0 = kept_s[par][0], k1 = kept_s[par][1];
        int n0 = __popcll(k0);
        int nk = n0 + __popcll(k1);
        u64 below = (1ull << lane) - 1;
        if ((k0 >> lane) & 1) klist[par][__popcll(k0 & below)] = lane;
        if ((k1 >> lane) & 1) klist[par][n0 + __popcll(k1 & below)] = 64 + lane;
        int nkc = (nk < 64) ? nk : 64;
        #pragma unroll
        for (int t = 0; t < 4; ++t) {
            int s = wv + (t << 4);
            bool has = s < nkc;
            int rr = klist[par][has ? s : 0];
            const u64* R = M + (size_t)(w0 * 64 + rr) * NW64;
            #pragma unroll
            for (int c = 0; c < 3; ++c) {
                int w = w0 + 4 + (c << 6) + lane;
                df[t][c] = (has && w < NW64) ? R[w] : 0ull;
            }
        }
        // rare overflow (nk > 64, early pairs): immediate load + commit.
        // Targets >= w0+4 are disjoint from next A's reads (w0+2, w0+3).
        for (int base = 64; base < nk; base += 64) {
            #pragma unroll
            for (int t = 0; t < 4; ++t) {
                int s = base + wv + (t << 4);
                bool has = s < nk;
                int rr = klist[par][has ? s : 0];
                const u64* R = M + (size_t)(w0 * 64 + rr) * NW64;
                #pragma unroll
                for (int c = 0; c < 3; ++c) {
                    int w = w0 + 4 + (c << 6) + lane;
                    u64 v2 = (has && w < NW64) ? R[w] : 0ull;
                    if (v2) atomicOr((unsigned long long*)&rem_s[w], (unsigned long long)v2);
                }
            }
        }
        // no second barrier: next A touches only rem_s (words w0+2/w0+3 were
        // finalized before this barrier) and opposite-parity kept_s/klist.
    }

    bar_sync();                                   // rem_s final for all waves

    for (int t = tid; t < NW64; t += 1024)
        rem_out[(size_t)b * NW64 + t] = rem_s[t];

    // ---- fused output tail (replaces out_kernel on the fast path) ----
    for (int t = tid; t < NTOT; t += 1024) {
        size_t idx = (size_t)b * NTOT + t;
        float4 box = sboxes[idx];
        u64 rw = rem_s[t >> 6];
        bool keep = (ssv[idx] != 0u) && !((rw >> (t & 63)) & 1ull);
        float sc = keep ? sscore[idx] : 0.0f;
        float* d = out + idx * 6;
        d[0] = box.x; d[1] = box.y; d[2] = box.z; d[3] = box.w;
        d[4] = sc;    d[5] = (float)scls[idx];
        out[(size_t)NBATCH * NTOT * 6 + idx] = keep ? 1.0f : 0.0f;
    }
}

// ---------------------------------------------------------------------------
// Fallback (small ws): original single-block NMS. Writes u32 words into the
// same u64 rem buffer (little-endian layout makes bit positions identical).
// ---------------------------------------------------------------------------
extern __shared__ unsigned char nms_smem[];

__global__ void __launch_bounds__(1024) nms_kernel(const float4* __restrict__ sboxes,
                                                   const uint32_t* __restrict__ ssv,
                                                   const int* __restrict__ nvalid_arr,
                                                   uint32_t* __restrict__ supp_out)
{
#pragma clang fp contract(off)
    int b = blockIdx.x;
    float4*   lbox = (float4*)nms_smem;
    uint32_t* supp = (uint32_t*)(nms_smem + (size_t)LDS_CAP * 16);
    uint32_t* svb  = supp + NW32;

    int nv = nvalid_arr[b];
    const float4* gb = sboxes + (size_t)b * NTOT;
    const uint32_t* gv = ssv + (size_t)b * NTOT;

    for (int t = threadIdx.x; t < NW32; t += 1024) { supp[t] = 0u; svb[t] = 0u; }
    __syncthreads();
    for (int t = threadIdx.x; t < nv; t += 1024) {
        if (t < LDS_CAP) lbox[t] = gb[t];
        if (gv[t]) atomicOr(&svb[t >> 5], 1u << (t & 31));
    }
    __syncthreads();

    for (int i = 0; i < nv; ++i) {
        uint32_t sw = supp[i >> 5];
        if ((sw >> (i & 31)) & 1u) continue;
        uint32_t vw = svb[i >> 5];
        if (!((vw >> (i & 31)) & 1u)) continue;

        float4 bi = (i < LDS_CAP) ? lbox[i] : gb[i];
        float ax1 = bi.x, ay1 = bi.y, ax2 = bi.z, ay2 = bi.w;
        float area_i = (ax2 - ax1) * (ay2 - ay1);

        for (int j = i + 1 + (int)threadIdx.x; j < nv; j += 1024) {
            float4 bj = (j < LDS_CAP) ? lbox[j] : gb[j];
            float xx1 = fmaxf(bj.x, ax1);
            float yy1 = fmaxf(bj.y, ay1);
            float xx2 = fminf(bj.z, ax2);
            float yy2 = fminf(bj.w, ay2);
            float w = fmaxf(xx2 - xx1, 0.0f);
            float h = fmaxf(yy2 - yy1, 0.0f);
            float inter  = w * h;
            float area_j = (bj.z - bj.x) * (bj.w - bj.y);
            float iou = inter / ((area_i + area_j) - inter);
            if (iou > IOU_THR_F) atomicOr(&supp[j >> 5], 1u << (j & 31));
        }
        __syncthreads();
    }

    __syncthreads();
    // u64 layout: u32 word w of image b lives at u32-index b*(2*NW64) + w
    for (int t = threadIdx.x; t < NW32; t += 1024)
        supp_out[(size_t)b * (2 * NW64) + t] = supp[t];
}

// ---------------------------------------------------------------------------
// Kernel D (fallback path only): assemble outputs
// ---------------------------------------------------------------------------
__global__ void out_kernel(const float4* __restrict__ sboxes, const float* __restrict__ sscore,
                           const int* __restrict__ scls, const uint32_t* __restrict__ ssv,
                           const u64* __restrict__ rem, float* __restrict__ out)
{
    int idx = blockIdx.x * 256 + threadIdx.x;
    if (idx >= NBATCH * NTOT) return;
    int b = idx / NTOT;
    int p = idx - b * NTOT;

    float4 box = sboxes[idx];
    u64 rw = rem[(size_t)b * NW64 + (p >> 6)];
    bool keep = (ssv[idx] != 0u) && !((rw >> (p & 63)) & 1ull);
    float sc = keep ? sscore[idx] : 0.0f;

    float* d = out + (size_t)idx * 6;
    d[0] = box.x; d[1] = box.y; d[2] = box.z; d[3] = box.w;
    d[4] = sc;    d[5] = (float)scls[idx];
    out[(size_t)NBATCH * NTOT * 6 + idx] = keep ? 1.0f : 0.0f;
}

// ---------------------------------------------------------------------------
extern "C" void kernel_launch(void* const* d_in, const int* in_sizes, int n_in,
                              void* d_out, int out_size, void* d_ws, size_t ws_size,
                              hipStream_t stream)
{
    const float* p3b = (const float*)d_in[0];
    const float* p3c = (const float*)d_in[1];
    const float* p3k = (const float*)d_in[2];
    const float* p4b = (const float*)d_in[3];
    const float* p4c = (const float*)d_in[4];
    const float* p4k = (const float*)d_in[5];
    const float* p5b = (const float*)d_in[6];
    const float* p5c = (const float*)d_in[7];
    const float* p5k = (const float*)d_in[8];
    float* out = (float*)d_out;

    // workspace carve-up (256B aligned slabs)
    char* ws = (char*)d_ws;
    size_t off = 0;
    auto alloc = [&](size_t bytes) { size_t o = off; off += (bytes + 255) & ~(size_t)255; return o; };
    const size_t BN = (size_t)NBATCH * NTOT;
    uint64_t* keys      = (uint64_t*)(ws + alloc(BN * 8));
    float4*   boxes_cat = (float4*)  (ws + alloc(BN * 16));
    float*    score     = (float*)   (ws + alloc(BN * 4));
    int*      clsidx    = (int*)     (ws + alloc(BN * 4));
    uint32_t* sv        = (uint32_t*)(ws + alloc(BN * 4));
    float4*   sboxes    = (float4*)  (ws + alloc(BN * 16));
    float*    sscore    = (float*)   (ws + alloc(BN * 4));
    int*      scls      = (int*)     (ws + alloc(BN * 4));
    uint32_t* ssv       = (uint32_t*)(ws + alloc(BN * 4));
    u64*      rem64     = (u64*)     (ws + alloc((size_t)NBATCH * NW64 * 8));
    u64*      validbits = (u64*)     (ws + alloc((size_t)NBATCH * NW64 * 8));
    int*      nvalid    = (int*)     (ws + alloc(NBATCH * 4));
    u64*      ldiag     = (u64*)     (ws + alloc((size_t)NBATCH * NW64 * 64 * 8));
    u64*      sdiag     = (u64*)     (ws + alloc((size_t)NBATCH * NW64 * 64 * 8));
    u64*      s2diag    = (u64*)     (ws + alloc((size_t)NBATCH * NW64 * 64 * 8));
    u64*      s3diag    = (u64*)     (ws + alloc((size_t)NBATCH * NW64 * 64 * 8));
    u64*      mask      = (u64*)     (ws + alloc((size_t)NBATCH * NTOT * NW64 * 8));
    bool fast = (off <= ws_size);

    int nblk = (int)((BN + 255) / 256);
    prep_kernel<<<nblk, 256, 0, stream>>>(p3b, p3c, p3k, p4b, p4c, p4k, p5b, p5c, p5k,
                                          keys, boxes_cat, score, clsidx, sv,
                                          validbits, nvalid);

    dim3 rgrid((NTOT + 255) / 256, NBATCH);
    rank_kernel<<<rgrid, 256, 0, stream>>>(keys, boxes_cat, score, clsidx, sv,
                                           sboxes, sscore, scls, ssv, validbits, nvalid);

    if (fast) {
        dim3 mgrid((NW64 + 3) / 4, NW64, NBATCH);
        mask_build<<<mgrid, 256, 0, stream>>>(sboxes, mask, ldiag, sdiag, s2diag, s3diag);
        resolve_kernel<<<NBATCH, 1024, 0, stream>>>(mask, ldiag, sdiag, s2diag, s3diag,
                                                    validbits, sboxes, sscore, scls, ssv,
                                                    rem64, out);
    } else {
        hipMemsetAsync(rem64, 0, (size_t)NBATCH * NW64 * 8, stream);
        size_t smem = (size_t)LDS_CAP * 16 + (size_t)NW32 * 4 * 2;
        smem = (smem + 15) & ~(size_t)15;
        hipFuncSetAttribute((const void*)nms_kernel, hipFuncAttributeMaxDynamicSharedMemorySize, (int)smem);
        nms_kernel<<<NBATCH, 1024, smem, stream>>>(sboxes, ssv, nvalid, (uint32_t*)rem64);
        out_kernel<<<nblk, 256, 0, stream>>>(sboxes, sscore, scls, ssv, rem64, out);
    }
}

// Round 12
// 522.647 us; speedup vs baseline: 2.2425x; 1.0514x over previous
//
#include <hip/hip_runtime.h>
#include <stdint.h>

#define NB3 8112
#define NB4 2028
#define NB5 507
#define NTOT 10647           // 8112 + 2028 + 507
#define NBATCH 4
#define NCLS 20
#define NW32 333             // ceil(10647 / 32)
#define NW64 167             // ceil(10647 / 64)
#define NPAIR 84             // ceil(NW64 / 2): 128-box groups for resolve
#define NTAIL 23             // NTOT - 64*(NW64-1)
#define LDS_CAP 9984         // boxes staged in LDS (fallback kernel)
#define CONF_THR_F 0.1f
#define IOU_THR_F 0.45f
// Upper midpoint of 0.45f: RN(x) > 0.45f  <=>  x > IOU_MID (0.45f mantissa LSB
// is even -> tie at the midpoint rounds DOWN). 25-bit m x 24-bit union is
// exact in f64, so (double)inter > IOU_MID*(double)union is bit-equivalent to
// the reference's f32-divide-then-compare.
#define IOU_MID ((double)IOU_THR_F + 0x1p-26)

typedef unsigned long long u64;

// ---------------------------------------------------------------------------
// Kernel A: per-box score / class argmax / sort key.
// Also zeroes validbits/nvalid (folds the two hipMemsetAsync dispatches).
// ---------------------------------------------------------------------------
__global__ void prep_kernel(const float* __restrict__ p3b, const float* __restrict__ p3c, const float* __restrict__ p3k,
                            const float* __restrict__ p4b, const float* __restrict__ p4c, const float* __restrict__ p4k,
                            const float* __restrict__ p5b, const float* __restrict__ p5c, const float* __restrict__ p5k,
                            uint64_t* __restrict__ keys, float4* __restrict__ boxes_cat,
                            float* __restrict__ score, int* __restrict__ clsidx, uint32_t* __restrict__ svout,
                            u64* __restrict__ validbits, int* __restrict__ nvalid)
{
#pragma clang fp contract(off)
    int idx = blockIdx.x * 256 + threadIdx.x;
    if (idx < NBATCH * NW64) validbits[idx] = 0ull;
    if (idx < NBATCH) nvalid[idx] = 0;
    if (idx >= NBATCH * NTOT) return;
    int b = idx / NTOT;
    int i = idx - b * NTOT;

    const float* bx; const float* cf; const float* cl; int n, off;
    if (i < NB3)            { bx = p3b; cf = p3c; cl = p3k; n = NB3; off = i; }
    else if (i < NB3 + NB4) { bx = p4b; cf = p4c; cl = p4k; n = NB4; off = i - NB3; }
    else                    { bx = p5b; cf = p5c; cl = p5k; n = NB5; off = i - NB3 - NB4; }

    size_t e = (size_t)b * n + off;
    float4 box = *(const float4*)(bx + e * 4);
    float conf = cf[e];
    const float* c = cl + e * NCLS;
    float m = c[0]; int mi = 0;
    #pragma unroll
    for (int k = 1; k < NCLS; ++k) { float v = c[k]; if (v > m) { m = v; mi = k; } }

    bool valid = conf > CONF_THR_F;
    float s = valid ? conf * m : 0.0f;           // exact: single f32 mul, no fma
    uint32_t sb = __float_as_uint(s);            // s >= 0 -> bits monotonic
    keys[idx]      = ((uint64_t)sb << 32) | (uint32_t)(0xFFFFFFFFu - (uint32_t)i);
    boxes_cat[idx] = box;
    score[idx]     = s;
    clsidx[idx]    = mi;
    svout[idx]     = valid ? 1u : 0u;
}

// ---------------------------------------------------------------------------
// Kernel B: stable descending rank sort (rank = #keys strictly greater),
// scatter sorted arrays, build valid bitmap (u64 words) per image
// ---------------------------------------------------------------------------
__global__ void rank_kernel(const uint64_t* __restrict__ keys,
                            const float4* __restrict__ boxes_cat,
                            const float* __restrict__ score,
                            const int* __restrict__ clsidx,
                            const uint32_t* __restrict__ sv,
                            float4* __restrict__ sboxes, float* __restrict__ sscore,
                            int* __restrict__ scls, uint32_t* __restrict__ ssv,
                            u64* __restrict__ validbits, int* __restrict__ nvalid)
{
    int b = blockIdx.y;
    int i = blockIdx.x * 256 + threadIdx.x;
    const uint64_t* kb = keys + (size_t)b * NTOT;
    uint64_t mykey = (i < NTOT) ? kb[i] : 0ull;

    __shared__ uint64_t tile[256];
    int rank = 0;
    for (int t0 = 0; t0 < NTOT; t0 += 256) {
        int j = t0 + threadIdx.x;
        tile[threadIdx.x] = (j < NTOT) ? kb[j] : 0ull;   // 0 never > any real key
        __syncthreads();
        #pragma unroll 8
        for (int t = 0; t < 256; ++t) rank += (tile[t] > mykey) ? 1 : 0;
        __syncthreads();
    }

    if (i < NTOT) {
        size_t src = (size_t)b * NTOT + i;
        size_t dst = (size_t)b * NTOT + rank;
        sboxes[dst] = boxes_cat[src];
        sscore[dst] = score[src];
        scls[dst]   = clsidx[src];
        uint32_t v  = sv[src];
        ssv[dst]    = v;
        if (v) {
            atomicOr(&validbits[(size_t)b * NW64 + (rank >> 6)], 1ull << (rank & 63));
            atomicMax(&nvalid[b], rank + 1);
        }
    }
}

// ---------------------------------------------------------------------------
// Kernel C1 (fast path): build suppression bit-matrix + band buffers.
// IoU predicate via exact f64 midpoint comparison (see IOU_MID).
// mask[(b*NTOT + i)*NW64 + c]: bit k set iff hit && c*64+k > i && c*64+k < NTOT.
// ldiag [(b*NW64+r)*64+lane] = raw hit row & ((1<<lane)-1): in-word EARLIER
//   suppressors (resolve's fixpoint masks validity/removal via U|K).
// s1..s5diag[(b*NW64+r)*64+lane] = mask word at column r+1..r+5 (unwritten
//   when that column >= NW64; resolve guards every use by target index).
// ---------------------------------------------------------------------------
__global__ void __launch_bounds__(256) mask_build(const float4* __restrict__ sboxes,
                                                  u64* __restrict__ mask,
                                                  u64* __restrict__ ldiag,
                                                  u64* __restrict__ s1diag,
                                                  u64* __restrict__ s2diag,
                                                  u64* __restrict__ s3diag,
                                                  u64* __restrict__ s4diag,
                                                  u64* __restrict__ s5diag)
{
#pragma clang fp contract(off)
    int c = blockIdx.y;
    if (c < blockIdx.x * 4) return;              // whole block below diagonal
    int b = blockIdx.z;
    int sub = threadIdx.x >> 6;
    int lane = threadIdx.x & 63;
    int r = blockIdx.x * 4 + sub;

    __shared__ float4 cb[64];
    __shared__ float  ca[64];
    if (threadIdx.x < 64) {
        int j = c * 64 + threadIdx.x;
        float4 bj = sboxes[(size_t)b * NTOT + (j < NTOT ? j : NTOT - 1)];
        cb[threadIdx.x] = bj;
        ca[threadIdx.x] = (bj.z - bj.x) * (bj.w - bj.y);
    }
    __syncthreads();

    if (r >= NW64 || c < r) return;              // wave below diagonal / OOB
    int i = r * 64 + lane;
    float4 bi = sboxes[(size_t)b * NTOT + (i < NTOT ? i : NTOT - 1)];
    float ax1 = bi.x, ay1 = bi.y, ax2 = bi.z, ay2 = bi.w;
    float area_i = (ax2 - ax1) * (ay2 - ay1);

    u64 hh = 0;
    #pragma unroll 8
    for (int k = 0; k < 64; ++k) {
        float4 bj = cb[k];
        float xx1 = fmaxf(bj.x, ax1);
        float yy1 = fmaxf(bj.y, ay1);
        float xx2 = fminf(bj.z, ax2);
        float yy2 = fminf(bj.w, ay2);
        float w = fmaxf(xx2 - xx1, 0.0f);
        float h = fmaxf(yy2 - yy1, 0.0f);
        float inter = w * h;
        float uni = (area_i + ca[k]) - inter;    // same f32 ops as reference
        bool hit = (double)inter > IOU_MID * (double)uni;   // == RN(inter/uni) > 0.45f
        hh |= (u64)hit << k;
    }

    if (i < NTOT) {
        u64 colmask = (c == NW64 - 1) ? ((1ull << NTAIL) - 1) : ~0ull;
        u64 mw = hh & colmask;
        size_t bl = ((size_t)b * NW64 + r) * 64 + lane;
        if (c == r) {
            u64 gtmask = (lane < 63) ? (~0ull << (lane + 1)) : 0ull;
            mask[((size_t)b * NTOT + i) * NW64 + c] = mw & gtmask;
            ldiag[bl] = hh & ((1ull << lane) - 1);
        } else {
            mask[((size_t)b * NTOT + i) * NW64 + c] = mw;
            if (c == r + 1) s1diag[bl] = mw;
            if (c == r + 2) s2diag[bl] = mw;
            if (c == r + 3) s3diag[bl] = mw;
            if (c == r + 4) s4diag[bl] = mw;
            if (c == r + 5) s5diag[bl] = mw;
        }
    }
}

// ---------------------------------------------------------------------------
// Kernel C2 (fast path): greedy resolve with OVERLAPPED schedule.
// Per iteration p (one barrier):
//   wave 0   : pair p decision -- in-word ballot fixpoints (word0, S1 via LDS
//              reduce, word1), sup plain-ORs to words 2p,2p+1 (sole writer),
//              near-word atomics to 2p+2..2p+5 from distance-2..5 (word0) /
//              1..4 (word1) register bands, write kept_s[p&1], prefetch
//              next pair's 11 bands.
//   waves1-15: pair p-1 worker phase (klist from kept_s[(p-1)&1]; commit df
//              issued at p-1 for pair p-2, targets >= 2p+2 -- disjoint from
//              wave 0's reads 2p,2p+1; issue far loads for pair p-1,
//              targets >= 2(p-1)+6; rare nk>64 overflow immediate).
// Contribution completeness for word 2p before iteration p reads it:
//   in-word/S1 (iter p), bands d1-d5 (iters p-1,p-2), far >= d6 of pairs
//   <= p-3 (committed <= iter p-1). All pre-barrier(p-1). Verified per-case.
// + fused output tail (block b writes image b's dets/keep from LDS rem_s).
// ---------------------------------------------------------------------------
static __device__ __forceinline__ void bar_sync()
{
    asm volatile("s_waitcnt lgkmcnt(0)" ::: "memory");
    __builtin_amdgcn_s_barrier();
    asm volatile("" ::: "memory");
}

static __device__ __forceinline__ u64 rfl64(u64 x)
{
    uint32_t lo = __builtin_amdgcn_readfirstlane((uint32_t)x);
    uint32_t hi = __builtin_amdgcn_readfirstlane((uint32_t)(x >> 32));
    return ((u64)hi << 32) | (u64)lo;
}

__global__ void __launch_bounds__(1024) resolve_kernel(const u64* __restrict__ mask,
                                                       const u64* __restrict__ ldiag,
                                                       const u64* __restrict__ s1diag,
                                                       const u64* __restrict__ s2diag,
                                                       const u64* __restrict__ s3diag,
                                                       const u64* __restrict__ s4diag,
                                                       const u64* __restrict__ s5diag,
                                                       const u64* __restrict__ validbits,
                                                       const float4* __restrict__ sboxes,
                                                       const float* __restrict__ sscore,
                                                       const int* __restrict__ scls,
                                                       const uint32_t* __restrict__ ssv,
                                                       u64* __restrict__ rem_out,
                                                       float* __restrict__ out)
{
    int b = blockIdx.x;
    int tid = threadIdx.x;
    int lane = tid & 63;
    int wv = tid >> 6;
    const u64* M  = mask   + (size_t)b * NTOT * NW64;
    const u64* LD = ldiag  + (size_t)b * NW64 * 64;
    const u64* S1A = s1diag + (size_t)b * NW64 * 64;
    const u64* S2A = s2diag + (size_t)b * NW64 * 64;
    const u64* S3A = s3diag + (size_t)b * NW64 * 64;
    const u64* S4A = s4diag + (size_t)b * NW64 * 64;
    const u64* S5A = s5diag + (size_t)b * NW64 * 64;
    const u64* V  = validbits + (size_t)b * NW64;

    __shared__ u64 rem_s[NW64 + 1];              // +1: word index 167 (pair tail)
    __shared__ u64 v_s[NW64 + 1];                // v_s[167] = 0 -> alive1 = 0
    __shared__ u64 kept_s[2][2];                 // parity double-buffered
    __shared__ int klist[2][128];
    __shared__ u64 sc_s;                         // wave-0 S1 reduction scratch

    for (int t = tid; t < NW64; t += 1024) { rem_s[t] = 0ull; v_s[t] = V[t]; }
    if (tid == 0) {
        rem_s[NW64] = 0ull; v_s[NW64] = 0ull;
        kept_s[0][0] = kept_s[0][1] = kept_s[1][0] = kept_s[1][1] = 0ull;
        klist[0][0] = 0; klist[1][0] = 0; sc_s = 0ull;
    }

    // wave 0's register bands for pair 0 (word0 = 0 needs d0..d5; word1 = 1
    // needs d0..d4). Distance-1 of word0 (s1_0) feeds the S1 cross-word OR.
    u64 ld0 = 0, s1_0 = 0, s2_0 = 0, s3_0 = 0, s4_0 = 0, s5_0 = 0;
    u64 ld1 = 0, s1_1 = 0, s2_1 = 0, s3_1 = 0, s4_1 = 0;
    if (wv == 0) {
        ld0 = LD[lane];
        s1_0 = S1A[lane]; s2_0 = S2A[lane]; s3_0 = S3A[lane];
        s4_0 = S4A[lane]; s5_0 = S5A[lane];
        ld1 = LD[64 + lane];
        s1_1 = S1A[64 + lane]; s2_1 = S2A[64 + lane];
        s3_1 = S3A[64 + lane]; s4_1 = S4A[64 + lane];
    }

    u64 df[5][3];                                // worker deferred far-OR payload
    #pragma unroll
    for (int t = 0; t < 5; ++t) {
        #pragma unroll
        for (int c = 0; c < 3; ++c) df[t][c] = 0ull;
    }

    bar_sync();

    for (int p = 0; p < NPAIR; ++p) {
        int par = p & 1;
        int w0 = 2 * p, w1 = 2 * p + 1;

        if (wv == 0) {
            // ---------------- wave 0: decide pair p ----------------
            u64 a0pre = rfl64(v_s[w0] & ~rem_s[w0]);
            u64 a1pre = rfl64(v_s[w1] & ~rem_s[w1]);   // w1==167 -> pad gives 0

            // word0 fixpoint
            u64 U = a0pre, K0 = 0;
            while (U) {
                u64 UK = U | K0;
                bool inU = (U >> lane) & 1;
                u64 nk = __ballot(inU && ((ld0 & UK) == 0ull));
                u64 nr = __ballot(inU && ((ld0 & K0) != 0ull));
                K0 |= nk;
                U &= ~(nk | nr);
            }

            // S1 = OR of s1_0 over word0's kept lanes (same-address LDS atomic)
            if (lane == 0) sc_s = 0ull;
            if (((K0 >> lane) & 1) && s1_0)
                atomicOr((unsigned long long*)&sc_s, (unsigned long long)s1_0);
            asm volatile("s_waitcnt lgkmcnt(0)" ::: "memory");
            u64 S1 = sc_s;

            // word1 fixpoint (word0's suppressions pre-applied -> exactly greedy)
            u64 U1 = a1pre & ~S1, K1 = 0;
            while (U1) {
                u64 UK = U1 | K1;
                bool inU = (U1 >> lane) & 1;
                u64 nk = __ballot(inU && ((ld1 & UK) == 0ull));
                u64 nr = __ballot(inU && ((ld1 & K1) != 0ull));
                K1 |= nk;
                U1 &= ~(nk | nr);
            }

            if (lane == 0) {
                kept_s[par][0] = K0; kept_s[par][1] = K1;
                u64 sup0 = a0pre & ~K0;            // wave 0 is sole writer of
                u64 sup1 = a1pre & ~K1;            // words 2p,2p+1 this iter
                if (sup0) rem_s[w0] |= sup0;
                if (sup1) rem_s[w1] |= sup1;
            }
            // near words 2p+2..2p+5 from register bands (guard by TARGET index;
            // band values are garbage when the source column chunk >= NW64)
            int w2 = w0 + 2, w3 = w0 + 3, w4 = w0 + 4, w5 = w0 + 5;
            bool h2 = w2 < NW64, h3 = w3 < NW64, h4 = w4 < NW64, h5 = w5 < NW64;
            if ((K0 >> lane) & 1) {
                if (h2 && s2_0) atomicOr((unsigned long long*)&rem_s[w2], (unsigned long long)s2_0);
                if (h3 && s3_0) atomicOr((unsigned long long*)&rem_s[w3], (unsigned long long)s3_0);
                if (h4 && s4_0) atomicOr((unsigned long long*)&rem_s[w4], (unsigned long long)s4_0);
                if (h5 && s5_0) atomicOr((unsigned long long*)&rem_s[w5], (unsigned long long)s5_0);
            }
            if ((K1 >> lane) & 1) {
                if (h2 && s1_1) atomicOr((unsigned long long*)&rem_s[w2], (unsigned long long)s1_1);
                if (h3 && s2_1) atomicOr((unsigned long long*)&rem_s[w3], (unsigned long long)s2_1);
                if (h4 && s3_1) atomicOr((unsigned long long*)&rem_s[w4], (unsigned long long)s3_1);
                if (h5 && s4_1) atomicOr((unsigned long long*)&rem_s[w5], (unsigned long long)s4_1);
            }
            // prefetch next pair's bands (consumed after next barrier)
            int pn = (p + 1 < NPAIR) ? p + 1 : p;
            int i0 = 2 * pn;
            int i1 = (2 * pn + 1 < NW64) ? 2 * pn + 1 : NW64 - 1;
            ld0  = LD [(size_t)i0 * 64 + lane];
            s1_0 = S1A[(size_t)i0 * 64 + lane];
            s2_0 = S2A[(size_t)i0 * 64 + lane];
            s3_0 = S3A[(size_t)i0 * 64 + lane];
            s4_0 = S4A[(size_t)i0 * 64 + lane];
            s5_0 = S5A[(size_t)i0 * 64 + lane];
            ld1  = LD [(size_t)i1 * 64 + lane];
            s1_1 = S1A[(size_t)i1 * 64 + lane];
            s2_1 = S2A[(size_t)i1 * 64 + lane];
            s3_1 = S3A[(size_t)i1 * 64 + lane];
            s4_1 = S4A[(size_t)i1 * 64 + lane];
        } else {
            // ---------------- workers: pair p-1 phase ----------------
            int parw = par ^ 1;
            u64 k0 = kept_s[parw][0], k1 = kept_s[parw][1];
            int n0 = __popcll(k0);
            int nk = n0 + __popcll(k1);
            u64 below = (1ull << lane) - 1;
            if ((k0 >> lane) & 1) klist[parw][__popcll(k0 & below)] = lane;
            if ((k1 >> lane) & 1) klist[parw][n0 + __popcll(k1 & below)] = 64 + lane;

            // commit df issued at p-1 for pair p-2 (targets >= 2p+2; wave 0
            // reads 2p,2p+1 concurrently -> disjoint)
            #pragma unroll
            for (int t = 0; t < 5; ++t) {
                #pragma unroll
                for (int c = 0; c < 3; ++c) {
                    if (df[t][c])
                        atomicOr((unsigned long long*)&rem_s[2 * p + 2 + (c << 6) + lane],
                                 (unsigned long long)df[t][c]);
                }
            }

            // issue far loads for pair p-1 (targets >= 2(p-1)+6), consumed at p+1
            int q = (p > 0) ? p - 1 : 0;
            int nkc = (nk < 64) ? nk : 64;
            #pragma unroll
            for (int t = 0; t < 5; ++t) {
                int s = (wv - 1) + t * 15;
                bool has = (p > 0) && (s < nkc);
                int rr = klist[parw][has ? s : 0];
                const u64* R = M + (size_t)(q * 128 + rr) * NW64;
                #pragma unroll
                for (int c = 0; c < 3; ++c) {
                    int w = 2 * q + 6 + (c << 6) + lane;
                    df[t][c] = (has && w < NW64) ? R[w] : 0ull;
                }
            }
            // rare overflow (nk > 64): immediate load + commit (targets >=
            // 2q+6 = 2p+4 -> disjoint from wave 0's reads)
            for (int base = 64; base < nk; base += 64) {
                #pragma unroll
                for (int t = 0; t < 5; ++t) {
                    int s = base + (wv - 1) + t * 15;
                    bool has = s < nk;
                    int rr = klist[parw][has ? s : 0];
                    const u64* R = M + (size_t)(q * 128 + rr) * NW64;
                    #pragma unroll
                    for (int c = 0; c < 3; ++c) {
                        int w = 2 * q + 6 + (c << 6) + lane;
                        u64 v2 = (has && w < NW64) ? R[w] : 0ull;
                        if (v2) atomicOr((unsigned long long*)&rem_s[w], (unsigned long long)v2);
                    }
                }
            }
        }

        bar_sync();                               // kept_s/rem_s coherent
    }

    // post-loop: all remaining df target words >= 2(NPAIR-2)+6 = 170 > 166,
    // so nothing is pending. rem_s is final.

    for (int t = tid; t < NW64; t += 1024)
        rem_out[(size_t)b * NW64 + t] = rem_s[t];

    // ---- fused output tail (replaces out_kernel on the fast path) ----
    for (int t = tid; t < NTOT; t += 1024) {
        size_t idx = (size_t)b * NTOT + t;
        float4 box = sboxes[idx];
        u64 rw = rem_s[t >> 6];
        bool keep = (ssv[idx] != 0u) && !((rw >> (t & 63)) & 1ull);
        float sc = keep ? sscore[idx] : 0.0f;
        float* d = out + idx * 6;
        d[0] = box.x; d[1] = box.y; d[2] = box.z; d[3] = box.w;
        d[4] = sc;    d[5] = (float)scls[idx];
        out[(size_t)NBATCH * NTOT * 6 + idx] = keep ? 1.0f : 0.0f;
    }
}

// ---------------------------------------------------------------------------
// Fallback (small ws): original single-block NMS. Writes u32 words into the
// same u64 rem buffer (little-endian layout makes bit positions identical).
// ---------------------------------------------------------------------------
extern __shared__ unsigned char nms_smem[];

__global__ void __launch_bounds__(1024) nms_kernel(const float4* __restrict__ sboxes,
                                                   const uint32_t* __restrict__ ssv,
                                                   const int* __restrict__ nvalid_arr,
                                                   uint32_t* __restrict__ supp_out)
{
#pragma clang fp contract(off)
    int b = blockIdx.x;
    float4*   lbox = (float4*)nms_smem;
    uint32_t* supp = (uint32_t*)(nms_smem + (size_t)LDS_CAP * 16);
    uint32_t* svb  = supp + NW32;

    int nv = nvalid_arr[b];
    const float4* gb = sboxes + (size_t)b * NTOT;
    const uint32_t* gv = ssv + (size_t)b * NTOT;

    for (int t = threadIdx.x; t < NW32; t += 1024) { supp[t] = 0u; svb[t] = 0u; }
    __syncthreads();
    for (int t = threadIdx.x; t < nv; t += 1024) {
        if (t < LDS_CAP) lbox[t] = gb[t];
        if (gv[t]) atomicOr(&svb[t >> 5], 1u << (t & 31));
    }
    __syncthreads();

    for (int i = 0; i < nv; ++i) {
        uint32_t sw = supp[i >> 5];
        if ((sw >> (i & 31)) & 1u) continue;
        uint32_t vw = svb[i >> 5];
        if (!((vw >> (i & 31)) & 1u)) continue;

        float4 bi = (i < LDS_CAP) ? lbox[i] : gb[i];
        float ax1 = bi.x, ay1 = bi.y, ax2 = bi.z, ay2 = bi.w;
        float area_i = (ax2 - ax1) * (ay2 - ay1);

        for (int j = i + 1 + (int)threadIdx.x; j < nv; j += 1024) {
            float4 bj = (j < LDS_CAP) ? lbox[j] : gb[j];
            float xx1 = fmaxf(bj.x, ax1);
            float yy1 = fmaxf(bj.y, ay1);
            float xx2 = fminf(bj.z, ax2);
            float yy2 = fminf(bj.w, ay2);
            float w = fmaxf(xx2 - xx1, 0.0f);
            float h = fmaxf(yy2 - yy1, 0.0f);
            float inter  = w * h;
            float area_j = (bj.z - bj.x) * (bj.w - bj.y);
            float iou = inter / ((area_i + area_j) - inter);
            if (iou > IOU_THR_F) atomicOr(&supp[j >> 5], 1u << (j & 31));
        }
        __syncthreads();
    }

    __syncthreads();
    // u64 layout: u32 word w of image b lives at u32-index b*(2*NW64) + w
    for (int t = threadIdx.x; t < NW32; t += 1024)
        supp_out[(size_t)b * (2 * NW64) + t] = supp[t];
}

// ---------------------------------------------------------------------------
// Kernel D (fallback path only): assemble outputs
// ---------------------------------------------------------------------------
__global__ void out_kernel(const float4* __restrict__ sboxes, const float* __restrict__ sscore,
                           const int* __restrict__ scls, const uint32_t* __restrict__ ssv,
                           const u64* __restrict__ rem, float* __restrict__ out)
{
    int idx = blockIdx.x * 256 + threadIdx.x;
    if (idx >= NBATCH * NTOT) return;
    int b = idx / NTOT;
    int p = idx - b * NTOT;

    float4 box = sboxes[idx];
    u64 rw = rem[(size_t)b * NW64 + (p >> 6)];
    bool keep = (ssv[idx] != 0u) && !((rw >> (p & 63)) & 1ull);
    float sc = keep ? sscore[idx] : 0.0f;

    float* d = out + (size_t)idx * 6;
    d[0] = box.x; d[1] = box.y; d[2] = box.z; d[3] = box.w;
    d[4] = sc;    d[5] = (float)scls[idx];
    out[(size_t)NBATCH * NTOT * 6 + idx] = keep ? 1.0f : 0.0f;
}

// ---------------------------------------------------------------------------
extern "C" void kernel_launch(void* const* d_in, const int* in_sizes, int n_in,
                              void* d_out, int out_size, void* d_ws, size_t ws_size,
                              hipStream_t stream)
{
    const float* p3b = (const float*)d_in[0];
    const float* p3c = (const float*)d_in[1];
    const float* p3k = (const float*)d_in[2];
    const float* p4b = (const float*)d_in[3];
    const float* p4c = (const float*)d_in[4];
    const float* p4k = (const float*)d_in[5];
    const float* p5b = (const float*)d_in[6];
    const float* p5c = (const float*)d_in[7];
    const float* p5k = (const float*)d_in[8];
    float* out = (float*)d_out;

    // workspace carve-up (256B aligned slabs)
    char* ws = (char*)d_ws;
    size_t off = 0;
    auto alloc = [&](size_t bytes) { size_t o = off; off += (bytes + 255) & ~(size_t)255; return o; };
    const size_t BN = (size_t)NBATCH * NTOT;
    uint64_t* keys      = (uint64_t*)(ws + alloc(BN * 8));
    float4*   boxes_cat = (float4*)  (ws + alloc(BN * 16));
    float*    score     = (float*)   (ws + alloc(BN * 4));
    int*      clsidx    = (int*)     (ws + alloc(BN * 4));
    uint32_t* sv        = (uint32_t*)(ws + alloc(BN * 4));
    float4*   sboxes    = (float4*)  (ws + alloc(BN * 16));
    float*    sscore    = (float*)   (ws + alloc(BN * 4));
    int*      scls      = (int*)     (ws + alloc(BN * 4));
    uint32_t* ssv       = (uint32_t*)(ws + alloc(BN * 4));
    u64*      rem64     = (u64*)     (ws + alloc((size_t)NBATCH * NW64 * 8));
    u64*      validbits = (u64*)     (ws + alloc((size_t)NBATCH * NW64 * 8));
    int*      nvalid    = (int*)     (ws + alloc(NBATCH * 4));
    u64*      ldiag     = (u64*)     (ws + alloc((size_t)NBATCH * NW64 * 64 * 8));
    u64*      s1diag    = (u64*)     (ws + alloc((size_t)NBATCH * NW64 * 64 * 8));
    u64*      s2diag    = (u64*)     (ws + alloc((size_t)NBATCH * NW64 * 64 * 8));
    u64*      s3diag    = (u64*)     (ws + alloc((size_t)NBATCH * NW64 * 64 * 8));
    u64*      s4diag    = (u64*)     (ws + alloc((size_t)NBATCH * NW64 * 64 * 8));
    u64*      s5diag    = (u64*)     (ws + alloc((size_t)NBATCH * NW64 * 64 * 8));
    u64*      mask      = (u64*)     (ws + alloc((size_t)NBATCH * NTOT * NW64 * 8));
    bool fast = (off <= ws_size);

    int nblk = (int)((BN + 255) / 256);
    prep_kernel<<<nblk, 256, 0, stream>>>(p3b, p3c, p3k, p4b, p4c, p4k, p5b, p5c, p5k,
                                          keys, boxes_cat, score, clsidx, sv,
                                          validbits, nvalid);

    dim3 rgrid((NTOT + 255) / 256, NBATCH);
    rank_kernel<<<rgrid, 256, 0, stream>>>(keys, boxes_cat, score, clsidx, sv,
                                           sboxes, sscore, scls, ssv, validbits, nvalid);

    if (fast) {
        dim3 mgrid((NW64 + 3) / 4, NW64, NBATCH);
        mask_build<<<mgrid, 256, 0, stream>>>(sboxes, mask, ldiag, s1diag, s2diag,
                                              s3diag, s4diag, s5diag);
        resolve_kernel<<<NBATCH, 1024, 0, stream>>>(mask, ldiag, s1diag, s2diag, s3diag,
                                                    s4diag, s5diag, validbits,
                                                    sboxes, sscore, scls, ssv,
                                                    rem64, out);
    } else {
        hipMemsetAsync(rem64, 0, (size_t)NBATCH * NW64 * 8, stream);
        size_t smem = (size_t)LDS_CAP * 16 + (size_t)NW32 * 4 * 2;
        smem = (smem + 15) & ~(size_t)15;
        hipFuncSetAttribute((const void*)nms_kernel, hipFuncAttributeMaxDynamicSharedMemorySize, (int)smem);
        nms_kernel<<<NBATCH, 1024, smem, stream>>>(sboxes, ssv, nvalid, (uint32_t*)rem64);
        out_kernel<<<nblk, 256, 0, stream>>>(sboxes, sscore, scls, ssv, rem64, out);
    }
}